// Round 1
// baseline (1611.088 us; speedup 1.0000x reference)
//
#include <hip/hip_runtime.h>
#include <cstdint>
#include <cstddef>

#define CDIV(a,b) (((a)+(b)-1)/(b))
constexpr int NG = 64;

__global__ void k_zero(int* p, long n) {
  long i = (long)blockIdx.x*blockDim.x + threadIdx.x;
  long stride = (long)gridDim.x*blockDim.x;
  for (; i < n; i += stride) p[i] = 0;
}

__global__ void k_hist(const int* __restrict__ dst, int* __restrict__ icnt, int E) {
  int e = blockIdx.x*blockDim.x + threadIdx.x;
  if (e < E) atomicAdd(&icnt[dst[e]], 1);
}

// per-node: dinv, selfnorm, CSR offsets (block scan + one atomic per block), graph histogram
__global__ void k_node(const int* __restrict__ icnt, const int* __restrict__ batch,
                       float* __restrict__ dinv, float* __restrict__ selfn,
                       int* __restrict__ offs, int* __restrict__ cursor,
                       int* __restrict__ cnt_g, int n) {
  __shared__ int scan[256];
  __shared__ int hist[NG];
  __shared__ int base;
  int tid = threadIdx.x;
  int i = blockIdx.x*256 + tid;
  if (tid < NG) hist[tid] = 0;
  int c = (i < n) ? icnt[i] : 0;
  scan[tid] = c;
  __syncthreads();
  for (int d = 1; d < 256; d <<= 1) {
    int t = (tid >= d) ? scan[tid-d] : 0;
    __syncthreads();
    scan[tid] += t;
    __syncthreads();
  }
  if (tid == 255) base = atomicAdd(cursor, scan[255]);
  __syncthreads();
  if (i < n) {
    offs[i] = base + scan[tid] - c;
    float deg = (float)(c + 1);
    dinv[i] = rsqrtf(deg);
    selfn[i] = 1.0f / deg;
    atomicAdd(&hist[batch[i]], 1);
  }
  __syncthreads();
  if (tid < NG && hist[tid]) atomicAdd(&cnt_g[tid], hist[tid]);
}

__global__ void k_fill(const int* __restrict__ src, const int* __restrict__ dst,
                       const float* __restrict__ dinv, const int* __restrict__ offs,
                       int* __restrict__ fill, int* __restrict__ col, float* __restrict__ wgt,
                       int E) {
  int e = blockIdx.x*blockDim.x + threadIdx.x;
  if (e >= E) return;
  int s = src[e], d = dst[e];
  int p = offs[d] + atomicAdd(&fill[d], 1);
  col[p] = s;
  wgt[p] = dinv[s] * dinv[d];
}

// z[i] = sum_{e: dst=i} w_e * y[src_e] + selfn[i]*y[i]   (+bias, relu for layer 1)
// one wave per node, lanes over features
template<int F, bool L1>
__global__ __launch_bounds__(256) void k_gather(
    const float* __restrict__ y, float* __restrict__ z,
    const int* __restrict__ col, const float* __restrict__ wgt,
    const int* __restrict__ offs, const int* __restrict__ icnt,
    const float* __restrict__ selfn, const float* __restrict__ bias, int n) {
  int gw = (int)((blockIdx.x*(size_t)blockDim.x + threadIdx.x) >> 6);
  int lane = threadIdx.x & 63;
  if (gw >= n) return;
  constexpr int V = F / 64;
  float acc[V];
  float sn = selfn[gw];
  if constexpr (V == 1) {
    acc[0] = y[(size_t)gw*F + lane] * sn;
  } else {
    float2 t = *(const float2*)(y + (size_t)gw*F + lane*2);
    acc[0] = t.x * sn; acc[1] = t.y * sn;
  }
  int e0 = offs[gw], ec = icnt[gw];
  int e = e0, eend = e0 + ec;
  for (; e + 1 < eend; e += 2) {
    int s0 = col[e], s1 = col[e+1];
    float w0 = wgt[e], w1 = wgt[e+1];
    if constexpr (V == 1) {
      float v0 = y[(size_t)s0*F + lane];
      float v1 = y[(size_t)s1*F + lane];
      acc[0] += v0*w0 + v1*w1;
    } else {
      float2 v0 = *(const float2*)(y + (size_t)s0*F + lane*2);
      float2 v1 = *(const float2*)(y + (size_t)s1*F + lane*2);
      acc[0] += v0.x*w0 + v1.x*w1;
      acc[1] += v0.y*w0 + v1.y*w1;
    }
  }
  if (e < eend) {
    int s0 = col[e]; float w0 = wgt[e];
    if constexpr (V == 1) {
      acc[0] += y[(size_t)s0*F + lane] * w0;
    } else {
      float2 v0 = *(const float2*)(y + (size_t)s0*F + lane*2);
      acc[0] += v0.x*w0; acc[1] += v0.y*w0;
    }
  }
  if constexpr (V == 1) {
    float o = acc[0];
    if constexpr (L1) { o += bias[lane]; o = fmaxf(o, 0.f); }
    z[(size_t)gw*F + lane] = o;
  } else {
    float o0 = acc[0], o1 = acc[1];
    if constexpr (L1) {
      o0 += bias[lane*2];   o0 = fmaxf(o0, 0.f);
      o1 += bias[lane*2+1]; o1 = fmaxf(o1, 0.f);
    }
    *(float2*)(z + (size_t)gw*F + lane*2) = make_float2(o0, o1);
  }
}

// C[n x nout] = A[n x K] @ W[K x nout], BM=BN=64, TM=TN=4, 256 threads
// EPI: 0=plain store, 1=bias+relu store, 2=bias+relu + fused graph-mean-pool accumulation (no store)
template<int K, int EPI>
__global__ __launch_bounds__(256) void k_gemm(
    const float* __restrict__ A, const float* __restrict__ W,
    const float* __restrict__ bias, float* __restrict__ C,
    int n, int nout, const int* __restrict__ batch, float* __restrict__ gsum) {
  constexpr int BM = 64, BN = 64;
  __shared__ float sA[BM][K + 4];
  __shared__ float sW[K][BN];
  __shared__ float red[16][BN];
  int row0 = blockIdx.x * BM, col0 = blockIdx.y * BN;
  int tid = threadIdx.x;
  for (int idx = tid; idx < BM*K; idx += 256) {
    int m = idx / K, k = idx % K;
    int r = row0 + m;
    sA[m][k] = (r < n) ? A[(size_t)r*K + k] : 0.f;
  }
  for (int idx = tid; idx < K*BN; idx += 256) {
    int k = idx / BN, c2 = idx % BN;
    sW[k][c2] = W[(size_t)k*nout + col0 + c2];
  }
  __syncthreads();
  int tx = tid & 15, ty = tid >> 4;
  float acc[4][4] = {};
  for (int k = 0; k < K; k += 4) {
    float4 av[4], wv[4];
    #pragma unroll
    for (int r = 0; r < 4; r++) av[r] = *(const float4*)&sA[ty*4 + r][k];
    #pragma unroll
    for (int j = 0; j < 4; j++) wv[j] = *(const float4*)&sW[k + j][tx*4];
    #pragma unroll
    for (int j = 0; j < 4; j++) {
      float4 wj = wv[j];
      #pragma unroll
      for (int r = 0; r < 4; r++) {
        float aj = (j == 0) ? av[r].x : (j == 1) ? av[r].y : (j == 2) ? av[r].z : av[r].w;
        acc[r][0] += aj * wj.x;
        acc[r][1] += aj * wj.y;
        acc[r][2] += aj * wj.z;
        acc[r][3] += aj * wj.w;
      }
    }
  }
  if constexpr (EPI >= 1) {
    float bv[4];
    #pragma unroll
    for (int c2 = 0; c2 < 4; c2++) bv[c2] = bias[col0 + tx*4 + c2];
    #pragma unroll
    for (int r = 0; r < 4; r++)
      #pragma unroll
      for (int c2 = 0; c2 < 4; c2++)
        acc[r][c2] = fmaxf(acc[r][c2] + bv[c2], 0.f);
  }
  if constexpr (EPI <= 1) {
    #pragma unroll
    for (int r = 0; r < 4; r++) {
      int row = row0 + ty*4 + r;
      if (row < n)
        *(float4*)&C[(size_t)row*nout + col0 + tx*4] =
            make_float4(acc[r][0], acc[r][1], acc[r][2], acc[r][3]);
    }
  } else {
    int g0 = batch[row0];
    int g1 = batch[min(row0 + BM - 1, n - 1)];
    for (int g = g0; g <= g1; ++g) {
      float p0 = 0, p1 = 0, p2 = 0, p3 = 0;
      #pragma unroll
      for (int r = 0; r < 4; r++) {
        int row = row0 + ty*4 + r;
        if (row < n && batch[row] == g) {
          p0 += acc[r][0]; p1 += acc[r][1]; p2 += acc[r][2]; p3 += acc[r][3];
        }
      }
      red[ty][tx*4+0] = p0; red[ty][tx*4+1] = p1;
      red[ty][tx*4+2] = p2; red[ty][tx*4+3] = p3;
      __syncthreads();
      if (tid < BN) {
        float s = 0;
        #pragma unroll
        for (int j = 0; j < 16; j++) s += red[j][tid];
        atomicAdd(&gsum[g*256 + col0 + tid], s);
      }
      __syncthreads();
    }
  }
}

__device__ __forceinline__ float sigm(float x) { return 1.f / (1.f + expf(-x)); }

// per-graph: mean-pool finish + both LSTM directions (T=1, zero state) + FC + log_softmax
__global__ __launch_bounds__(256) void k_head(
    const float* __restrict__ gsum, const int* __restrict__ cnt_g,
    const float* __restrict__ wf, const float* __restrict__ bf,
    const float* __restrict__ wb, const float* __restrict__ bb,
    const float* __restrict__ fw, const float* __restrict__ fb,
    float* __restrict__ out) {
  int g = blockIdx.x, tid = threadIdx.x;
  __shared__ float pooled[256];
  __shared__ float gatesf[512], gatesb[512];
  __shared__ float lstm[256];
  __shared__ float sred[256];
  float invc = 1.0f / fmaxf((float)cnt_g[g], 1.0f);
  pooled[tid] = gsum[g*256 + tid] * invc;
  __syncthreads();
  #pragma unroll
  for (int half = 0; half < 2; ++half) {
    int j = tid + half*256;
    float df = bf[j], db = bb[j];
    const float4* wfj = (const float4*)(wf + (size_t)j*256);
    const float4* wbj = (const float4*)(wb + (size_t)j*256);
    for (int k4 = 0; k4 < 64; k4++) {
      float4 p4 = *(const float4*)&pooled[k4*4];
      float4 a = wfj[k4], b = wbj[k4];
      df += p4.x*a.x + p4.y*a.y + p4.z*a.z + p4.w*a.w;
      db += p4.x*b.x + p4.y*b.y + p4.z*b.z + p4.w*b.w;
    }
    gatesf[j] = df; gatesb[j] = db;
  }
  __syncthreads();
  if (tid < 128) {
    float i = gatesf[tid], gg = gatesf[256+tid], o = gatesf[384+tid];
    float cc = sigm(i) * tanhf(gg);
    lstm[tid] = sigm(o) * tanhf(cc);
  } else {
    int u = tid - 128;
    float i = gatesb[u], gg = gatesb[256+u], o = gatesb[384+u];
    float cc = sigm(i) * tanhf(gg);
    lstm[128+u] = sigm(o) * tanhf(cc);
  }
  __syncthreads();
  float l0 = fb[tid];
  float l1 = (tid < 244) ? fb[tid + 256] : 0.f;
  for (int k = 0; k < 256; k++) {
    float pk = lstm[k];
    l0 += pk * fw[k*500 + tid];
    if (tid < 244) l1 += pk * fw[k*500 + tid + 256];
  }
  float m = (tid < 244) ? fmaxf(l0, l1) : l0;
  sred[tid] = m; __syncthreads();
  for (int d = 128; d > 0; d >>= 1) {
    if (tid < d) sred[tid] = fmaxf(sred[tid], sred[tid+d]);
    __syncthreads();
  }
  float mx = sred[0]; __syncthreads();
  float s = expf(l0 - mx) + ((tid < 244) ? expf(l1 - mx) : 0.f);
  sred[tid] = s; __syncthreads();
  for (int d = 128; d > 0; d >>= 1) {
    if (tid < d) sred[tid] += sred[tid+d];
    __syncthreads();
  }
  float lse = logf(sred[0]) + mx;
  out[g*500 + tid] = l0 - lse;
  if (tid < 244) out[g*500 + tid + 256] = l1 - lse;
}

extern "C" void kernel_launch(void* const* d_in, const int* in_sizes, int n_in,
                              void* d_out, int out_size, void* d_ws, size_t ws_size,
                              hipStream_t stream) {
  const float* x     = (const float*)d_in[0];
  const int*   ei    = (const int*)d_in[1];
  const int*   batch = (const int*)d_in[2];
  const float* W1 = (const float*)d_in[3];  const float* b1 = (const float*)d_in[4];
  const float* W2 = (const float*)d_in[5];  const float* b2 = (const float*)d_in[6];
  const float* W3 = (const float*)d_in[7];  const float* b3 = (const float*)d_in[8];
  const float* wf = (const float*)d_in[9];  const float* bf = (const float*)d_in[11];
  const float* wb = (const float*)d_in[12]; const float* bb = (const float*)d_in[14];
  const float* fw = (const float*)d_in[15]; const float* fb = (const float*)d_in[16];
  int N = in_sizes[2];
  int E = in_sizes[1] / 2;
  const int* src = ei;
  const int* dst = ei + E;

  char* w = (char*)d_ws;
  auto alloc = [&](size_t bytes) { char* p = w; w += (bytes + 255) / 256 * 256; return p; };
  int*   icnt   = (int*)  alloc((size_t)N*4);
  int*   fill   = (int*)  alloc((size_t)N*4);
  int*   cnt_g  = (int*)  alloc(NG*4);
  int*   cursor = (int*)  alloc(256);
  float* gsum   = (float*)alloc(NG*256*4);
  char*  zero_end = w;
  int*   offs  = (int*)  alloc((size_t)N*4);
  float* dinv  = (float*)alloc((size_t)N*4);
  float* selfn = (float*)alloc((size_t)N*4);
  int*   col   = (int*)  alloc((size_t)E*4);
  float* wgt   = (float*)alloc((size_t)E*4);
  float* B0    = (float*)alloc((size_t)N*128*4);
  float* B1    = (float*)alloc((size_t)N*128*4);

  long zwords = (zero_end - (char*)icnt) / 4;
  k_zero<<<256, 256, 0, stream>>>(icnt, zwords);
  k_hist<<<CDIV(E,256), 256, 0, stream>>>(dst, icnt, E);
  k_node<<<CDIV(N,256), 256, 0, stream>>>(icnt, batch, dinv, selfn, offs, cursor, cnt_g, N);
  k_fill<<<CDIV(E,256), 256, 0, stream>>>(src, dst, dinv, offs, fill, col, wgt, E);

  // layer 1: y1 = x @ W1 (N x 64), then gather at F=64 with bias+relu -> h1
  k_gemm<128,0><<<dim3(CDIV(N,64),1), 256, 0, stream>>>(x, W1, nullptr, B0, N, 64, nullptr, nullptr);
  k_gather<64,true><<<CDIV(N,4), 256, 0, stream>>>(B0, B1, col, wgt, offs, icnt, selfn, b1, N);
  // layer 2: gather at F=64 -> z2, then h2 = relu(z2 @ W2 + b2) (N x 128)
  k_gather<64,false><<<CDIV(N,4), 256, 0, stream>>>(B1, B0, col, wgt, offs, icnt, selfn, nullptr, N);
  k_gemm<64,1><<<dim3(CDIV(N,64),2), 256, 0, stream>>>(B0, W2, b2, B1, N, 128, nullptr, nullptr);
  // layer 3: gather at F=128 -> z3, then fused relu(z3 @ W3 + b3) + graph-sum pooling
  k_gather<128,false><<<CDIV(N,4), 256, 0, stream>>>(B1, B0, col, wgt, offs, icnt, selfn, nullptr, N);
  k_gemm<128,2><<<dim3(CDIV(N,64),4), 256, 0, stream>>>(B0, W3, b3, nullptr, N, 256, batch, gsum);
  // head: pool-mean + bi-LSTM(T=1) + FC + log_softmax
  k_head<<<NG, 256, 0, stream>>>(gsum, cnt_g, wf, bf, wb, bb, fw, fb, (float*)d_out);
}

// Round 2
// 728.225 us; speedup vs baseline: 2.2123x; 2.2123x over previous
//
#include <hip/hip_runtime.h>
#include <cstdint>
#include <cstddef>

#define CDIV(a,b) (((a)+(b)-1)/(b))
constexpr int NG = 64;

__global__ void k_zero(int* p, long n) {
  long i = (long)blockIdx.x*blockDim.x + threadIdx.x;
  long stride = (long)gridDim.x*blockDim.x;
  for (; i < n; i += stride) p[i] = 0;
}

__global__ void k_hist(const int* __restrict__ dst, int* __restrict__ icnt, int E) {
  int e = blockIdx.x*blockDim.x + threadIdx.x;
  if (e < E) atomicAdd(&icnt[dst[e]], 1);
}

// per-node: dinv, selfnorm, CSR offsets (block scan + one atomic per block), graph histogram
__global__ void k_node(const int* __restrict__ icnt, const int* __restrict__ batch,
                       float* __restrict__ dinv, float* __restrict__ selfn,
                       int* __restrict__ offs, int* __restrict__ cursor,
                       int* __restrict__ cnt_g, int n) {
  __shared__ int scan[256];
  __shared__ int hist[NG];
  __shared__ int base;
  int tid = threadIdx.x;
  int i = blockIdx.x*256 + tid;
  if (tid < NG) hist[tid] = 0;
  int c = (i < n) ? icnt[i] : 0;
  scan[tid] = c;
  __syncthreads();
  for (int d = 1; d < 256; d <<= 1) {
    int t = (tid >= d) ? scan[tid-d] : 0;
    __syncthreads();
    scan[tid] += t;
    __syncthreads();
  }
  if (tid == 255) base = atomicAdd(cursor, scan[255]);
  __syncthreads();
  if (i < n) {
    offs[i] = base + scan[tid] - c;
    float deg = (float)(c + 1);
    dinv[i] = rsqrtf(deg);
    selfn[i] = 1.0f / deg;
    atomicAdd(&hist[batch[i]], 1);
  }
  __syncthreads();
  if (tid < NG && hist[tid]) atomicAdd(&cnt_g[tid], hist[tid]);
}

__global__ void k_fill(const int* __restrict__ src, const int* __restrict__ dst,
                       const float* __restrict__ dinv, const int* __restrict__ offs,
                       int* __restrict__ fill, int* __restrict__ col, float* __restrict__ wgt,
                       int E) {
  int e = blockIdx.x*blockDim.x + threadIdx.x;
  if (e >= E) return;
  int s = src[e], d = dst[e];
  int p = offs[d] + atomicAdd(&fill[d], 1);
  col[p] = s;
  wgt[p] = dinv[s] * dinv[d];
}

// z[i] = sum_{e: dst=i} w_e * y[src_e] + selfn[i]*y[i]   (+bias, relu for layer 1)
// one wave per node, lanes over features
template<int F, bool L1>
__global__ __launch_bounds__(256) void k_gather(
    const float* __restrict__ y, float* __restrict__ z,
    const int* __restrict__ col, const float* __restrict__ wgt,
    const int* __restrict__ offs, const int* __restrict__ icnt,
    const float* __restrict__ selfn, const float* __restrict__ bias, int n) {
  int gw = (int)((blockIdx.x*(size_t)blockDim.x + threadIdx.x) >> 6);
  int lane = threadIdx.x & 63;
  if (gw >= n) return;
  constexpr int V = F / 64;
  float acc[V];
  float sn = selfn[gw];
  if constexpr (V == 1) {
    acc[0] = y[(size_t)gw*F + lane] * sn;
  } else {
    float2 t = *(const float2*)(y + (size_t)gw*F + lane*2);
    acc[0] = t.x * sn; acc[1] = t.y * sn;
  }
  int e0 = offs[gw], ec = icnt[gw];
  int e = e0, eend = e0 + ec;
  for (; e + 1 < eend; e += 2) {
    int s0 = col[e], s1 = col[e+1];
    float w0 = wgt[e], w1 = wgt[e+1];
    if constexpr (V == 1) {
      float v0 = y[(size_t)s0*F + lane];
      float v1 = y[(size_t)s1*F + lane];
      acc[0] += v0*w0 + v1*w1;
    } else {
      float2 v0 = *(const float2*)(y + (size_t)s0*F + lane*2);
      float2 v1 = *(const float2*)(y + (size_t)s1*F + lane*2);
      acc[0] += v0.x*w0 + v1.x*w1;
      acc[1] += v0.y*w0 + v1.y*w1;
    }
  }
  if (e < eend) {
    int s0 = col[e]; float w0 = wgt[e];
    if constexpr (V == 1) {
      acc[0] += y[(size_t)s0*F + lane] * w0;
    } else {
      float2 v0 = *(const float2*)(y + (size_t)s0*F + lane*2);
      acc[0] += v0.x*w0; acc[1] += v0.y*w0;
    }
  }
  if constexpr (V == 1) {
    float o = acc[0];
    if constexpr (L1) { o += bias[lane]; o = fmaxf(o, 0.f); }
    z[(size_t)gw*F + lane] = o;
  } else {
    float o0 = acc[0], o1 = acc[1];
    if constexpr (L1) {
      o0 += bias[lane*2];   o0 = fmaxf(o0, 0.f);
      o1 += bias[lane*2+1]; o1 = fmaxf(o1, 0.f);
    }
    *(float2*)(z + (size_t)gw*F + lane*2) = make_float2(o0, o1);
  }
}

// C[n x nout] = A[n x K] @ W[K x nout], BM=BN=64, TM=TN=4, 256 threads.
// K chunked by KC=32 (small LDS, no giant unroll -> no VGPR spill).
// EPI: 0=plain store, 1=bias+relu store, 2=bias+relu + fused graph-mean-pool accumulation (no store)
template<int K, int EPI>
__global__ __launch_bounds__(256, 4) void k_gemm(
    const float* __restrict__ A, const float* __restrict__ W,
    const float* __restrict__ bias, float* __restrict__ C,
    int n, int nout, const int* __restrict__ batch, float* __restrict__ gsum) {
  constexpr int BM = 64, BN = 64, KC = 32;
  __shared__ float sA[BM][KC + 4];   // 64 x 36 floats = 9216 B
  __shared__ float sW[KC][BN];       // 32 x 64 floats = 8192 B
  __shared__ float red[16][BN];      // 4096 B (EPI==2 only)
  int row0 = blockIdx.x * BM, col0 = blockIdx.y * BN;
  int tid = threadIdx.x;
  int tx = tid & 15, ty = tid >> 4;
  float acc[4][4] = {};

  // loader indices (constant across chunks)
  int la_r  = tid >> 3;        // 0..31  (A rows, two passes)
  int la_c4 = tid & 7;         // 0..7   (A float4 column within chunk)
  int lw_k  = tid >> 4;        // 0..15  (W rows, two passes)
  int lw_c4 = tid & 15;        // 0..15  (W float4 column)

  for (int kc = 0; kc < K; kc += KC) {
    #pragma unroll
    for (int rr = 0; rr < BM; rr += 32) {
      int row = row0 + la_r + rr;
      float4 v = (row < n) ? *(const float4*)&A[(size_t)row*K + kc + la_c4*4]
                           : make_float4(0.f, 0.f, 0.f, 0.f);
      *(float4*)&sA[la_r + rr][la_c4*4] = v;
    }
    #pragma unroll
    for (int kk = 0; kk < KC; kk += 16) {
      float4 v = *(const float4*)&W[(size_t)(kc + lw_k + kk)*nout + col0 + lw_c4*4];
      *(float4*)&sW[lw_k + kk][lw_c4*4] = v;
    }
    __syncthreads();

    #pragma unroll 1
    for (int k = 0; k < KC; k += 4) {
      float4 av[4], wv[4];
      #pragma unroll
      for (int r = 0; r < 4; r++) av[r] = *(const float4*)&sA[ty*4 + r][k];
      #pragma unroll
      for (int j = 0; j < 4; j++) wv[j] = *(const float4*)&sW[k + j][tx*4];
      #pragma unroll
      for (int j = 0; j < 4; j++) {
        float4 wj = wv[j];
        #pragma unroll
        for (int r = 0; r < 4; r++) {
          float aj = (j == 0) ? av[r].x : (j == 1) ? av[r].y : (j == 2) ? av[r].z : av[r].w;
          acc[r][0] += aj * wj.x;
          acc[r][1] += aj * wj.y;
          acc[r][2] += aj * wj.z;
          acc[r][3] += aj * wj.w;
        }
      }
    }
    __syncthreads();
  }

  if constexpr (EPI >= 1) {
    float bv[4];
    #pragma unroll
    for (int c2 = 0; c2 < 4; c2++) bv[c2] = bias[col0 + tx*4 + c2];
    #pragma unroll
    for (int r = 0; r < 4; r++)
      #pragma unroll
      for (int c2 = 0; c2 < 4; c2++)
        acc[r][c2] = fmaxf(acc[r][c2] + bv[c2], 0.f);
  }
  if constexpr (EPI <= 1) {
    #pragma unroll
    for (int r = 0; r < 4; r++) {
      int row = row0 + ty*4 + r;
      if (row < n)
        *(float4*)&C[(size_t)row*nout + col0 + tx*4] =
            make_float4(acc[r][0], acc[r][1], acc[r][2], acc[r][3]);
    }
  } else {
    int g0 = batch[row0];
    int g1 = batch[min(row0 + BM - 1, n - 1)];
    for (int g = g0; g <= g1; ++g) {
      float p0 = 0, p1 = 0, p2 = 0, p3 = 0;
      #pragma unroll
      for (int r = 0; r < 4; r++) {
        int row = row0 + ty*4 + r;
        if (row < n && batch[row] == g) {
          p0 += acc[r][0]; p1 += acc[r][1]; p2 += acc[r][2]; p3 += acc[r][3];
        }
      }
      red[ty][tx*4+0] = p0; red[ty][tx*4+1] = p1;
      red[ty][tx*4+2] = p2; red[ty][tx*4+3] = p3;
      __syncthreads();
      if (tid < BN) {
        float s = 0;
        #pragma unroll
        for (int j = 0; j < 16; j++) s += red[j][tid];
        atomicAdd(&gsum[g*256 + col0 + tid], s);
      }
      __syncthreads();
    }
  }
}

__device__ __forceinline__ float sigm(float x) { return 1.f / (1.f + expf(-x)); }

// per-graph: mean-pool finish + both LSTM directions (T=1, zero state) + FC + log_softmax
__global__ __launch_bounds__(256) void k_head(
    const float* __restrict__ gsum, const int* __restrict__ cnt_g,
    const float* __restrict__ wf, const float* __restrict__ bf,
    const float* __restrict__ wb, const float* __restrict__ bb,
    const float* __restrict__ fw, const float* __restrict__ fb,
    float* __restrict__ out) {
  int g = blockIdx.x, tid = threadIdx.x;
  __shared__ float pooled[256];
  __shared__ float gatesf[512], gatesb[512];
  __shared__ float lstm[256];
  __shared__ float sred[256];
  float invc = 1.0f / fmaxf((float)cnt_g[g], 1.0f);
  pooled[tid] = gsum[g*256 + tid] * invc;
  __syncthreads();
  #pragma unroll
  for (int half = 0; half < 2; ++half) {
    int j = tid + half*256;
    float df = bf[j], db = bb[j];
    const float4* wfj = (const float4*)(wf + (size_t)j*256);
    const float4* wbj = (const float4*)(wb + (size_t)j*256);
    for (int k4 = 0; k4 < 64; k4++) {
      float4 p4 = *(const float4*)&pooled[k4*4];
      float4 a = wfj[k4], b = wbj[k4];
      df += p4.x*a.x + p4.y*a.y + p4.z*a.z + p4.w*a.w;
      db += p4.x*b.x + p4.y*b.y + p4.z*b.z + p4.w*b.w;
    }
    gatesf[j] = df; gatesb[j] = db;
  }
  __syncthreads();
  if (tid < 128) {
    float i = gatesf[tid], gg = gatesf[256+tid], o = gatesf[384+tid];
    float cc = sigm(i) * tanhf(gg);
    lstm[tid] = sigm(o) * tanhf(cc);
  } else {
    int u = tid - 128;
    float i = gatesb[u], gg = gatesb[256+u], o = gatesb[384+u];
    float cc = sigm(i) * tanhf(gg);
    lstm[128+u] = sigm(o) * tanhf(cc);
  }
  __syncthreads();
  float l0 = fb[tid];
  float l1 = (tid < 244) ? fb[tid + 256] : 0.f;
  for (int k = 0; k < 256; k++) {
    float pk = lstm[k];
    l0 += pk * fw[k*500 + tid];
    if (tid < 244) l1 += pk * fw[k*500 + tid + 256];
  }
  float m = (tid < 244) ? fmaxf(l0, l1) : l0;
  sred[tid] = m; __syncthreads();
  for (int d = 128; d > 0; d >>= 1) {
    if (tid < d) sred[tid] = fmaxf(sred[tid], sred[tid+d]);
    __syncthreads();
  }
  float mx = sred[0]; __syncthreads();
  float s = expf(l0 - mx) + ((tid < 244) ? expf(l1 - mx) : 0.f);
  sred[tid] = s; __syncthreads();
  for (int d = 128; d > 0; d >>= 1) {
    if (tid < d) sred[tid] += sred[tid+d];
    __syncthreads();
  }
  float lse = logf(sred[0]) + mx;
  out[g*500 + tid] = l0 - lse;
  if (tid < 244) out[g*500 + tid + 256] = l1 - lse;
}

extern "C" void kernel_launch(void* const* d_in, const int* in_sizes, int n_in,
                              void* d_out, int out_size, void* d_ws, size_t ws_size,
                              hipStream_t stream) {
  const float* x     = (const float*)d_in[0];
  const int*   ei    = (const int*)d_in[1];
  const int*   batch = (const int*)d_in[2];
  const float* W1 = (const float*)d_in[3];  const float* b1 = (const float*)d_in[4];
  const float* W2 = (const float*)d_in[5];  const float* b2 = (const float*)d_in[6];
  const float* W3 = (const float*)d_in[7];  const float* b3 = (const float*)d_in[8];
  const float* wf = (const float*)d_in[9];  const float* bf = (const float*)d_in[11];
  const float* wb = (const float*)d_in[12]; const float* bb = (const float*)d_in[14];
  const float* fw = (const float*)d_in[15]; const float* fb = (const float*)d_in[16];
  int N = in_sizes[2];
  int E = in_sizes[1] / 2;
  const int* src = ei;
  const int* dst = ei + E;

  char* w = (char*)d_ws;
  auto alloc = [&](size_t bytes) { char* p = w; w += (bytes + 255) / 256 * 256; return p; };
  int*   icnt   = (int*)  alloc((size_t)N*4);
  int*   fill   = (int*)  alloc((size_t)N*4);
  int*   cnt_g  = (int*)  alloc(NG*4);
  int*   cursor = (int*)  alloc(256);
  float* gsum   = (float*)alloc(NG*256*4);
  char*  zero_end = w;
  int*   offs  = (int*)  alloc((size_t)N*4);
  float* dinv  = (float*)alloc((size_t)N*4);
  float* selfn = (float*)alloc((size_t)N*4);
  int*   col   = (int*)  alloc((size_t)E*4);
  float* wgt   = (float*)alloc((size_t)E*4);
  float* B0    = (float*)alloc((size_t)N*128*4);
  float* B1    = (float*)alloc((size_t)N*128*4);

  long zwords = (zero_end - (char*)icnt) / 4;
  k_zero<<<256, 256, 0, stream>>>(icnt, zwords);
  k_hist<<<CDIV(E,256), 256, 0, stream>>>(dst, icnt, E);
  k_node<<<CDIV(N,256), 256, 0, stream>>>(icnt, batch, dinv, selfn, offs, cursor, cnt_g, N);
  k_fill<<<CDIV(E,256), 256, 0, stream>>>(src, dst, dinv, offs, fill, col, wgt, E);

  // layer 1: y1 = x @ W1 (N x 64), then gather at F=64 with bias+relu -> h1
  k_gemm<128,0><<<dim3(CDIV(N,64),1), 256, 0, stream>>>(x, W1, nullptr, B0, N, 64, nullptr, nullptr);
  k_gather<64,true><<<CDIV(N,4), 256, 0, stream>>>(B0, B1, col, wgt, offs, icnt, selfn, b1, N);
  // layer 2: gather at F=64 -> z2, then h2 = relu(z2 @ W2 + b2) (N x 128)
  k_gather<64,false><<<CDIV(N,4), 256, 0, stream>>>(B1, B0, col, wgt, offs, icnt, selfn, nullptr, N);
  k_gemm<64,1><<<dim3(CDIV(N,64),2), 256, 0, stream>>>(B0, W2, b2, B1, N, 128, nullptr, nullptr);
  // layer 3: gather at F=128 -> z3, then fused relu(z3 @ W3 + b3) + graph-sum pooling
  k_gather<128,false><<<CDIV(N,4), 256, 0, stream>>>(B1, B0, col, wgt, offs, icnt, selfn, nullptr, N);
  k_gemm<128,2><<<dim3(CDIV(N,64),4), 256, 0, stream>>>(B0, W3, b3, nullptr, N, 256, batch, gsum);
  // head: pool-mean + bi-LSTM(T=1) + FC + log_softmax
  k_head<<<NG, 256, 0, stream>>>(gsum, cnt_g, wf, bf, wb, bb, fw, fb, (float*)d_out);
}

// Round 3
// 671.572 us; speedup vs baseline: 2.3990x; 1.0844x over previous
//
#include <hip/hip_runtime.h>
#include <cstdint>
#include <cstddef>

#define CDIV(a,b) (((a)+(b)-1)/(b))
constexpr int NG = 64;

__global__ void k_zero(int* p, long n) {
  long i = (long)blockIdx.x*blockDim.x + threadIdx.x;
  long stride = (long)gridDim.x*blockDim.x;
  for (; i < n; i += stride) p[i] = 0;
}

__global__ void k_hist(const int* __restrict__ dst, int* __restrict__ icnt, int E) {
  int e = blockIdx.x*blockDim.x + threadIdx.x;
  if (e < E) atomicAdd(&icnt[dst[e]], 1);
}

// per-node: dinv, selfnorm, CSR offsets (block scan + one atomic per block), graph histogram
__global__ void k_node(const int* __restrict__ icnt, const int* __restrict__ batch,
                       float* __restrict__ dinv, float* __restrict__ selfn,
                       int* __restrict__ offs, int* __restrict__ cursor,
                       int* __restrict__ cnt_g, int n) {
  __shared__ int scan[256];
  __shared__ int hist[NG];
  __shared__ int base;
  int tid = threadIdx.x;
  int i = blockIdx.x*256 + tid;
  if (tid < NG) hist[tid] = 0;
  int c = (i < n) ? icnt[i] : 0;
  scan[tid] = c;
  __syncthreads();
  for (int d = 1; d < 256; d <<= 1) {
    int t = (tid >= d) ? scan[tid-d] : 0;
    __syncthreads();
    scan[tid] += t;
    __syncthreads();
  }
  if (tid == 255) base = atomicAdd(cursor, scan[255]);
  __syncthreads();
  if (i < n) {
    offs[i] = base + scan[tid] - c;
    float deg = (float)(c + 1);
    dinv[i] = rsqrtf(deg);
    selfn[i] = 1.0f / deg;
    atomicAdd(&hist[batch[i]], 1);
  }
  __syncthreads();
  if (tid < NG && hist[tid]) atomicAdd(&cnt_g[tid], hist[tid]);
}

__global__ void k_fill(const int* __restrict__ src, const int* __restrict__ dst,
                       const float* __restrict__ dinv, const int* __restrict__ offs,
                       int* __restrict__ fill, int* __restrict__ col, float* __restrict__ wgt,
                       int E) {
  int e = blockIdx.x*blockDim.x + threadIdx.x;
  if (e >= E) return;
  int s = src[e], d = dst[e];
  int p = offs[d] + atomicAdd(&fill[d], 1);
  col[p] = s;
  wgt[p] = dinv[s] * dinv[d];
}

// z[i] = sum_{e: dst=i} w_e * y[src_e] + selfn[i]*y[i]   (+bias, relu for layer 1)
// one wave per node, lanes over features; edge loop unrolled x4 for MLP
template<int F, bool L1>
__global__ __launch_bounds__(256) void k_gather(
    const float* __restrict__ y, float* __restrict__ z,
    const int* __restrict__ col, const float* __restrict__ wgt,
    const int* __restrict__ offs, const int* __restrict__ icnt,
    const float* __restrict__ selfn, const float* __restrict__ bias, int n) {
  int gw = (int)((blockIdx.x*(size_t)blockDim.x + threadIdx.x) >> 6);
  int lane = threadIdx.x & 63;
  if (gw >= n) return;
  constexpr int V = F / 64;
  float acc[V];
  float sn = selfn[gw];
  if constexpr (V == 1) {
    acc[0] = y[(size_t)gw*F + lane] * sn;
  } else {
    float2 t = *(const float2*)(y + (size_t)gw*F + lane*2);
    acc[0] = t.x * sn; acc[1] = t.y * sn;
  }
  int e0 = offs[gw], ec = icnt[gw];
  int e = e0, eend = e0 + ec;
  for (; e + 3 < eend; e += 4) {
    int s0 = col[e], s1 = col[e+1], s2 = col[e+2], s3 = col[e+3];
    float w0 = wgt[e], w1 = wgt[e+1], w2 = wgt[e+2], w3 = wgt[e+3];
    if constexpr (V == 1) {
      float v0 = y[(size_t)s0*F + lane];
      float v1 = y[(size_t)s1*F + lane];
      float v2 = y[(size_t)s2*F + lane];
      float v3 = y[(size_t)s3*F + lane];
      acc[0] += v0*w0 + v1*w1 + v2*w2 + v3*w3;
    } else {
      float2 v0 = *(const float2*)(y + (size_t)s0*F + lane*2);
      float2 v1 = *(const float2*)(y + (size_t)s1*F + lane*2);
      float2 v2 = *(const float2*)(y + (size_t)s2*F + lane*2);
      float2 v3 = *(const float2*)(y + (size_t)s3*F + lane*2);
      acc[0] += v0.x*w0 + v1.x*w1 + v2.x*w2 + v3.x*w3;
      acc[1] += v0.y*w0 + v1.y*w1 + v2.y*w2 + v3.y*w3;
    }
  }
  for (; e < eend; e++) {
    int s0 = col[e]; float w0 = wgt[e];
    if constexpr (V == 1) {
      acc[0] += y[(size_t)s0*F + lane] * w0;
    } else {
      float2 v0 = *(const float2*)(y + (size_t)s0*F + lane*2);
      acc[0] += v0.x*w0; acc[1] += v0.y*w0;
    }
  }
  if constexpr (V == 1) {
    float o = acc[0];
    if constexpr (L1) { o += bias[lane]; o = fmaxf(o, 0.f); }
    z[(size_t)gw*F + lane] = o;
  } else {
    float o0 = acc[0], o1 = acc[1];
    if constexpr (L1) {
      o0 += bias[lane*2];   o0 = fmaxf(o0, 0.f);
      o1 += bias[lane*2+1]; o1 = fmaxf(o1, 0.f);
    }
    *(float2*)(z + (size_t)gw*F + lane*2) = make_float2(o0, o1);
  }
}

// C[n x nout] = A[n x K] @ W[K x nout], BM=BN=64, TM=TN=4, 256 threads.
// K chunked by KC=32 (small LDS, no giant unroll -> no VGPR spill).
// EPI: 0=plain store, 1=bias+relu store, 2=bias+relu + fused graph-mean-pool accumulation (no store)
template<int K, int EPI>
__global__ __launch_bounds__(256, 4) void k_gemm(
    const float* __restrict__ A, const float* __restrict__ W,
    const float* __restrict__ bias, float* __restrict__ C,
    int n, int nout, const int* __restrict__ batch, float* __restrict__ gsum) {
  constexpr int BM = 64, BN = 64, KC = 32;
  __shared__ float sA[BM][KC + 4];
  __shared__ float sW[KC][BN];
  __shared__ float red[16][BN];
  int row0 = blockIdx.x * BM, col0 = blockIdx.y * BN;
  int tid = threadIdx.x;
  int tx = tid & 15, ty = tid >> 4;
  float acc[4][4] = {};

  int la_r  = tid >> 3;
  int la_c4 = tid & 7;
  int lw_k  = tid >> 4;
  int lw_c4 = tid & 15;

  for (int kc = 0; kc < K; kc += KC) {
    #pragma unroll
    for (int rr = 0; rr < BM; rr += 32) {
      int row = row0 + la_r + rr;
      float4 v = (row < n) ? *(const float4*)&A[(size_t)row*K + kc + la_c4*4]
                           : make_float4(0.f, 0.f, 0.f, 0.f);
      *(float4*)&sA[la_r + rr][la_c4*4] = v;
    }
    #pragma unroll
    for (int kk = 0; kk < KC; kk += 16) {
      float4 v = *(const float4*)&W[(size_t)(kc + lw_k + kk)*nout + col0 + lw_c4*4];
      *(float4*)&sW[lw_k + kk][lw_c4*4] = v;
    }
    __syncthreads();

    #pragma unroll 1
    for (int k = 0; k < KC; k += 4) {
      float4 av[4], wv[4];
      #pragma unroll
      for (int r = 0; r < 4; r++) av[r] = *(const float4*)&sA[ty*4 + r][k];
      #pragma unroll
      for (int j = 0; j < 4; j++) wv[j] = *(const float4*)&sW[k + j][tx*4];
      #pragma unroll
      for (int j = 0; j < 4; j++) {
        float4 wj = wv[j];
        #pragma unroll
        for (int r = 0; r < 4; r++) {
          float aj = (j == 0) ? av[r].x : (j == 1) ? av[r].y : (j == 2) ? av[r].z : av[r].w;
          acc[r][0] += aj * wj.x;
          acc[r][1] += aj * wj.y;
          acc[r][2] += aj * wj.z;
          acc[r][3] += aj * wj.w;
        }
      }
    }
    __syncthreads();
  }

  if constexpr (EPI >= 1) {
    float bv[4];
    #pragma unroll
    for (int c2 = 0; c2 < 4; c2++) bv[c2] = bias[col0 + tx*4 + c2];
    #pragma unroll
    for (int r = 0; r < 4; r++)
      #pragma unroll
      for (int c2 = 0; c2 < 4; c2++)
        acc[r][c2] = fmaxf(acc[r][c2] + bv[c2], 0.f);
  }
  if constexpr (EPI <= 1) {
    #pragma unroll
    for (int r = 0; r < 4; r++) {
      int row = row0 + ty*4 + r;
      if (row < n)
        *(float4*)&C[(size_t)row*nout + col0 + tx*4] =
            make_float4(acc[r][0], acc[r][1], acc[r][2], acc[r][3]);
    }
  } else {
    int g0 = batch[row0];
    int g1 = batch[min(row0 + BM - 1, n - 1)];
    for (int g = g0; g <= g1; ++g) {
      float p0 = 0, p1 = 0, p2 = 0, p3 = 0;
      #pragma unroll
      for (int r = 0; r < 4; r++) {
        int row = row0 + ty*4 + r;
        if (row < n && batch[row] == g) {
          p0 += acc[r][0]; p1 += acc[r][1]; p2 += acc[r][2]; p3 += acc[r][3];
        }
      }
      red[ty][tx*4+0] = p0; red[ty][tx*4+1] = p1;
      red[ty][tx*4+2] = p2; red[ty][tx*4+3] = p3;
      __syncthreads();
      if (tid < BN) {
        float s = 0;
        #pragma unroll
        for (int j = 0; j < 16; j++) s += red[j][tid];
        atomicAdd(&gsum[g*256 + col0 + tid], s);
      }
      __syncthreads();
    }
  }
}

__device__ __forceinline__ float sigm(float x) { return 1.f / (1.f + expf(-x)); }

// per-graph: mean-pool finish + both LSTM directions (T=1, zero state) + FC + log_softmax.
// Gate GEMV: wave-per-gate-set, lanes span k (coalesced), shfl_xor reduce, 8 gates in flight.
__global__ __launch_bounds__(256) void k_head(
    const float* __restrict__ gsum, const int* __restrict__ cnt_g,
    const float* __restrict__ wf, const float* __restrict__ bf,
    const float* __restrict__ wb, const float* __restrict__ bb,
    const float* __restrict__ fw, const float* __restrict__ fb,
    float* __restrict__ out) {
  int g = blockIdx.x, tid = threadIdx.x;
  __shared__ float pooled[256];
  __shared__ float gatesf[512], gatesb[512];
  __shared__ float lstm[256];
  __shared__ float sred[256];
  float invc = 1.0f / fmaxf((float)cnt_g[g], 1.0f);
  pooled[tid] = gsum[g*256 + tid] * invc;
  __syncthreads();

  int wave = tid >> 6, lane = tid & 63;
  float4 p4 = *(const float4*)&pooled[lane*4];
  // wave 0,1 -> forward gates [0..256),[256..512); wave 2,3 -> backward
  const float* wsel = (wave < 2) ? wf : wb;
  const float* bsel = (wave < 2) ? bf : bb;
  float* gout = (wave < 2) ? gatesf : gatesb;
  int j0 = (wave & 1) * 256;
  for (int jj = 0; jj < 256; jj += 8) {
    float part[8];
    #pragma unroll
    for (int u = 0; u < 8; u++) {
      float4 w4 = *(const float4*)&wsel[(size_t)(j0 + jj + u)*256 + lane*4];
      part[u] = w4.x*p4.x + w4.y*p4.y + w4.z*p4.z + w4.w*p4.w;
    }
    #pragma unroll
    for (int u = 0; u < 8; u++) {
      #pragma unroll
      for (int off = 32; off > 0; off >>= 1)
        part[u] += __shfl_xor(part[u], off, 64);
    }
    float v = part[0];
    #pragma unroll
    for (int u = 1; u < 8; u++) v = (lane == u) ? part[u] : v;   // static indices only
    if (lane < 8) gout[j0 + jj + lane] = v + bsel[j0 + jj + lane];
  }
  __syncthreads();

  if (tid < 128) {
    float i = gatesf[tid], gg = gatesf[256+tid], o = gatesf[384+tid];
    float cc = sigm(i) * tanhf(gg);
    lstm[tid] = sigm(o) * tanhf(cc);
  } else {
    int u = tid - 128;
    float i = gatesb[u], gg = gatesb[256+u], o = gatesb[384+u];
    float cc = sigm(i) * tanhf(gg);
    lstm[128+u] = sigm(o) * tanhf(cc);
  }
  __syncthreads();

  float l0 = fb[tid];
  float l1 = (tid < 244) ? fb[tid + 256] : 0.f;
  #pragma unroll 4
  for (int k = 0; k < 256; k++) {
    float pk = lstm[k];
    l0 += pk * fw[k*500 + tid];
    if (tid < 244) l1 += pk * fw[k*500 + tid + 256];
  }
  float m = (tid < 244) ? fmaxf(l0, l1) : l0;
  sred[tid] = m; __syncthreads();
  for (int d = 128; d > 0; d >>= 1) {
    if (tid < d) sred[tid] = fmaxf(sred[tid], sred[tid+d]);
    __syncthreads();
  }
  float mx = sred[0]; __syncthreads();
  float s = expf(l0 - mx) + ((tid < 244) ? expf(l1 - mx) : 0.f);
  sred[tid] = s; __syncthreads();
  for (int d = 128; d > 0; d >>= 1) {
    if (tid < d) sred[tid] += sred[tid+d];
    __syncthreads();
  }
  float lse = logf(sred[0]) + mx;
  out[g*500 + tid] = l0 - lse;
  if (tid < 244) out[g*500 + tid + 256] = l1 - lse;
}

extern "C" void kernel_launch(void* const* d_in, const int* in_sizes, int n_in,
                              void* d_out, int out_size, void* d_ws, size_t ws_size,
                              hipStream_t stream) {
  const float* x     = (const float*)d_in[0];
  const int*   ei    = (const int*)d_in[1];
  const int*   batch = (const int*)d_in[2];
  const float* W1 = (const float*)d_in[3];  const float* b1 = (const float*)d_in[4];
  const float* W2 = (const float*)d_in[5];  const float* b2 = (const float*)d_in[6];
  const float* W3 = (const float*)d_in[7];  const float* b3 = (const float*)d_in[8];
  const float* wf = (const float*)d_in[9];  const float* bf = (const float*)d_in[11];
  const float* wb = (const float*)d_in[12]; const float* bb = (const float*)d_in[14];
  const float* fw = (const float*)d_in[15]; const float* fb = (const float*)d_in[16];
  int N = in_sizes[2];
  int E = in_sizes[1] / 2;
  const int* src = ei;
  const int* dst = ei + E;

  char* w = (char*)d_ws;
  auto alloc = [&](size_t bytes) { char* p = w; w += (bytes + 255) / 256 * 256; return p; };
  int*   icnt   = (int*)  alloc((size_t)N*4);
  int*   fill   = (int*)  alloc((size_t)N*4);
  int*   cnt_g  = (int*)  alloc(NG*4);
  int*   cursor = (int*)  alloc(256);
  float* gsum   = (float*)alloc(NG*256*4);
  char*  zero_end = w;
  int*   offs  = (int*)  alloc((size_t)N*4);
  float* dinv  = (float*)alloc((size_t)N*4);
  float* selfn = (float*)alloc((size_t)N*4);
  int*   col   = (int*)  alloc((size_t)E*4);
  float* wgt   = (float*)alloc((size_t)E*4);
  float* B0    = (float*)alloc((size_t)N*128*4);
  float* B1    = (float*)alloc((size_t)N*128*4);

  long zwords = (zero_end - (char*)icnt) / 4;
  k_zero<<<256, 256, 0, stream>>>(icnt, zwords);
  k_hist<<<CDIV(E,256), 256, 0, stream>>>(dst, icnt, E);
  k_node<<<CDIV(N,256), 256, 0, stream>>>(icnt, batch, dinv, selfn, offs, cursor, cnt_g, N);
  k_fill<<<CDIV(E,256), 256, 0, stream>>>(src, dst, dinv, offs, fill, col, wgt, E);

  // layer 1: y1 = x @ W1 (N x 64), then gather at F=64 with bias+relu -> h1
  k_gemm<128,0><<<dim3(CDIV(N,64),1), 256, 0, stream>>>(x, W1, nullptr, B0, N, 64, nullptr, nullptr);
  k_gather<64,true><<<CDIV(N,4), 256, 0, stream>>>(B0, B1, col, wgt, offs, icnt, selfn, b1, N);
  // layer 2: gather at F=64 -> z2, then h2 = relu(z2 @ W2 + b2) (N x 128)
  k_gather<64,false><<<CDIV(N,4), 256, 0, stream>>>(B1, B0, col, wgt, offs, icnt, selfn, nullptr, N);
  k_gemm<64,1><<<dim3(CDIV(N,64),2), 256, 0, stream>>>(B0, W2, b2, B1, N, 128, nullptr, nullptr);
  // layer 3: gather at F=128 -> z3, then fused relu(z3 @ W3 + b3) + graph-sum pooling
  k_gather<128,false><<<CDIV(N,4), 256, 0, stream>>>(B1, B0, col, wgt, offs, icnt, selfn, nullptr, N);
  k_gemm<128,2><<<dim3(CDIV(N,64),4), 256, 0, stream>>>(B0, W3, b3, nullptr, N, 256, batch, gsum);
  // head: pool-mean + bi-LSTM(T=1) + FC + log_softmax
  k_head<<<NG, 256, 0, stream>>>(gsum, cnt_g, wf, bf, wb, bb, fw, fb, (float*)d_out);
}

// Round 4
// 581.899 us; speedup vs baseline: 2.7687x; 1.1541x over previous
//
#include <hip/hip_runtime.h>
#include <cstdint>
#include <cstddef>

#define CDIV(a,b) (((a)+(b)-1)/(b))
constexpr int NG = 64;

__global__ void k_zero(int* p, long n) {
  long i = (long)blockIdx.x*blockDim.x + threadIdx.x;
  long stride = (long)gridDim.x*blockDim.x;
  for (; i < n; i += stride) p[i] = 0;
}

__global__ void k_hist(const int* __restrict__ dst, int* __restrict__ icnt, int E) {
  int e = blockIdx.x*blockDim.x + threadIdx.x;
  if (e < E) atomicAdd(&icnt[dst[e]], 1);
}

// per-node: dinv, selfnorm, CSR offsets (block scan + one atomic per block), graph histogram
__global__ void k_node(const int* __restrict__ icnt, const int* __restrict__ batch,
                       float* __restrict__ dinv, float* __restrict__ selfn,
                       int* __restrict__ offs, int* __restrict__ cursor,
                       int* __restrict__ cnt_g, int n) {
  __shared__ int scan[256];
  __shared__ int hist[NG];
  __shared__ int base;
  int tid = threadIdx.x;
  int i = blockIdx.x*256 + tid;
  if (tid < NG) hist[tid] = 0;
  int c = (i < n) ? icnt[i] : 0;
  scan[tid] = c;
  __syncthreads();
  for (int d = 1; d < 256; d <<= 1) {
    int t = (tid >= d) ? scan[tid-d] : 0;
    __syncthreads();
    scan[tid] += t;
    __syncthreads();
  }
  if (tid == 255) base = atomicAdd(cursor, scan[255]);
  __syncthreads();
  if (i < n) {
    offs[i] = base + scan[tid] - c;
    float deg = (float)(c + 1);
    dinv[i] = rsqrtf(deg);
    selfn[i] = 1.0f / deg;
    atomicAdd(&hist[batch[i]], 1);
  }
  __syncthreads();
  if (tid < NG && hist[tid]) atomicAdd(&cnt_g[tid], hist[tid]);
}

__global__ void k_fill(const int* __restrict__ src, const int* __restrict__ dst,
                       const float* __restrict__ dinv, const int* __restrict__ offs,
                       int* __restrict__ fill, int* __restrict__ col, float* __restrict__ wgt,
                       int E) {
  int e = blockIdx.x*blockDim.x + threadIdx.x;
  if (e >= E) return;
  int s = src[e], d = dst[e];
  int p = offs[d] + atomicAdd(&fill[d], 1);
  col[p] = s;
  wgt[p] = dinv[s] * dinv[d];
}

// z[i] = sum_{e: dst=i} w_e * y[src_e] + selfn[i]*y[i]   (+bias, relu for layer 1)
// one wave per node, lanes over features; edge loop unrolled x4 for MLP
template<int F, bool L1>
__global__ __launch_bounds__(256) void k_gather(
    const float* __restrict__ y, float* __restrict__ z,
    const int* __restrict__ col, const float* __restrict__ wgt,
    const int* __restrict__ offs, const int* __restrict__ icnt,
    const float* __restrict__ selfn, const float* __restrict__ bias, int n) {
  int gw = (int)((blockIdx.x*(size_t)blockDim.x + threadIdx.x) >> 6);
  int lane = threadIdx.x & 63;
  if (gw >= n) return;
  constexpr int V = F / 64;
  float acc[V];
  float sn = selfn[gw];
  if constexpr (V == 1) {
    acc[0] = y[(size_t)gw*F + lane] * sn;
  } else {
    float2 t = *(const float2*)(y + (size_t)gw*F + lane*2);
    acc[0] = t.x * sn; acc[1] = t.y * sn;
  }
  int e0 = offs[gw], ec = icnt[gw];
  int e = e0, eend = e0 + ec;
  for (; e + 3 < eend; e += 4) {
    int s0 = col[e], s1 = col[e+1], s2 = col[e+2], s3 = col[e+3];
    float w0 = wgt[e], w1 = wgt[e+1], w2 = wgt[e+2], w3 = wgt[e+3];
    if constexpr (V == 1) {
      float v0 = y[(size_t)s0*F + lane];
      float v1 = y[(size_t)s1*F + lane];
      float v2 = y[(size_t)s2*F + lane];
      float v3 = y[(size_t)s3*F + lane];
      acc[0] += v0*w0 + v1*w1 + v2*w2 + v3*w3;
    } else {
      float2 v0 = *(const float2*)(y + (size_t)s0*F + lane*2);
      float2 v1 = *(const float2*)(y + (size_t)s1*F + lane*2);
      float2 v2 = *(const float2*)(y + (size_t)s2*F + lane*2);
      float2 v3 = *(const float2*)(y + (size_t)s3*F + lane*2);
      acc[0] += v0.x*w0 + v1.x*w1 + v2.x*w2 + v3.x*w3;
      acc[1] += v0.y*w0 + v1.y*w1 + v2.y*w2 + v3.y*w3;
    }
  }
  for (; e < eend; e++) {
    int s0 = col[e]; float w0 = wgt[e];
    if constexpr (V == 1) {
      acc[0] += y[(size_t)s0*F + lane] * w0;
    } else {
      float2 v0 = *(const float2*)(y + (size_t)s0*F + lane*2);
      acc[0] += v0.x*w0; acc[1] += v0.y*w0;
    }
  }
  if constexpr (V == 1) {
    float o = acc[0];
    if constexpr (L1) { o += bias[lane]; o = fmaxf(o, 0.f); }
    z[(size_t)gw*F + lane] = o;
  } else {
    float o0 = acc[0], o1 = acc[1];
    if constexpr (L1) {
      o0 += bias[lane*2];   o0 = fmaxf(o0, 0.f);
      o1 += bias[lane*2+1]; o1 = fmaxf(o1, 0.f);
    }
    *(float2*)(z + (size_t)gw*F + lane*2) = make_float2(o0, o1);
  }
}

// C[n x nout] = A[n x K] @ W[K x nout], BM=BN=64, TM=TN=4, 256 threads.
// K chunked by KC=32 (small LDS, no giant unroll -> no VGPR spill).
// EPI: 0=plain store, 1=bias+relu store, 2=bias+relu + fused graph-mean-pool accumulation (no store)
template<int K, int EPI>
__global__ __launch_bounds__(256, 4) void k_gemm(
    const float* __restrict__ A, const float* __restrict__ W,
    const float* __restrict__ bias, float* __restrict__ C,
    int n, int nout, const int* __restrict__ batch, float* __restrict__ gsum) {
  constexpr int BM = 64, BN = 64, KC = 32;
  __shared__ float sA[BM][KC + 4];
  __shared__ float sW[KC][BN];
  __shared__ float red[16][BN];
  int row0 = blockIdx.x * BM, col0 = blockIdx.y * BN;
  int tid = threadIdx.x;
  int tx = tid & 15, ty = tid >> 4;
  float acc[4][4] = {};

  int la_r  = tid >> 3;
  int la_c4 = tid & 7;
  int lw_k  = tid >> 4;
  int lw_c4 = tid & 15;

  for (int kc = 0; kc < K; kc += KC) {
    #pragma unroll
    for (int rr = 0; rr < BM; rr += 32) {
      int row = row0 + la_r + rr;
      float4 v = (row < n) ? *(const float4*)&A[(size_t)row*K + kc + la_c4*4]
                           : make_float4(0.f, 0.f, 0.f, 0.f);
      *(float4*)&sA[la_r + rr][la_c4*4] = v;
    }
    #pragma unroll
    for (int kk = 0; kk < KC; kk += 16) {
      float4 v = *(const float4*)&W[(size_t)(kc + lw_k + kk)*nout + col0 + lw_c4*4];
      *(float4*)&sW[lw_k + kk][lw_c4*4] = v;
    }
    __syncthreads();

    #pragma unroll 1
    for (int k = 0; k < KC; k += 4) {
      float4 av[4], wv[4];
      #pragma unroll
      for (int r = 0; r < 4; r++) av[r] = *(const float4*)&sA[ty*4 + r][k];
      #pragma unroll
      for (int j = 0; j < 4; j++) wv[j] = *(const float4*)&sW[k + j][tx*4];
      #pragma unroll
      for (int j = 0; j < 4; j++) {
        float4 wj = wv[j];
        #pragma unroll
        for (int r = 0; r < 4; r++) {
          float aj = (j == 0) ? av[r].x : (j == 1) ? av[r].y : (j == 2) ? av[r].z : av[r].w;
          acc[r][0] += aj * wj.x;
          acc[r][1] += aj * wj.y;
          acc[r][2] += aj * wj.z;
          acc[r][3] += aj * wj.w;
        }
      }
    }
    __syncthreads();
  }

  if constexpr (EPI >= 1) {
    float bv[4];
    #pragma unroll
    for (int c2 = 0; c2 < 4; c2++) bv[c2] = bias[col0 + tx*4 + c2];
    #pragma unroll
    for (int r = 0; r < 4; r++)
      #pragma unroll
      for (int c2 = 0; c2 < 4; c2++)
        acc[r][c2] = fmaxf(acc[r][c2] + bv[c2], 0.f);
  }
  if constexpr (EPI <= 1) {
    #pragma unroll
    for (int r = 0; r < 4; r++) {
      int row = row0 + ty*4 + r;
      if (row < n)
        *(float4*)&C[(size_t)row*nout + col0 + tx*4] =
            make_float4(acc[r][0], acc[r][1], acc[r][2], acc[r][3]);
    }
  } else {
    int g0 = batch[row0];
    int g1 = batch[min(row0 + BM - 1, n - 1)];
    for (int g = g0; g <= g1; ++g) {
      float p0 = 0, p1 = 0, p2 = 0, p3 = 0;
      #pragma unroll
      for (int r = 0; r < 4; r++) {
        int row = row0 + ty*4 + r;
        if (row < n && batch[row] == g) {
          p0 += acc[r][0]; p1 += acc[r][1]; p2 += acc[r][2]; p3 += acc[r][3];
        }
      }
      red[ty][tx*4+0] = p0; red[ty][tx*4+1] = p1;
      red[ty][tx*4+2] = p2; red[ty][tx*4+3] = p3;
      __syncthreads();
      if (tid < BN) {
        float s = 0;
        #pragma unroll
        for (int j = 0; j < 16; j++) s += red[j][tid];
        atomicAdd(&gsum[g*256 + col0 + tid], s);
      }
      __syncthreads();
    }
  }
}

__device__ __forceinline__ float sigm(float x) { return 1.f / (1.f + expf(-x)); }

// gates[g][j] for j in [0,1024): [0,512)=forward, [512,1024)=backward.
// grid (16, 64); 4 threads per gate (k-quarters), 16 float4 loads in flight.
__global__ __launch_bounds__(256) void k_gates(
    const float* __restrict__ gsum, const int* __restrict__ cnt_g,
    const float* __restrict__ wf, const float* __restrict__ bf,
    const float* __restrict__ wb, const float* __restrict__ bb,
    float* __restrict__ gates) {
  int g = blockIdx.y;
  int j0 = blockIdx.x * 64;
  int tid = threadIdx.x;
  __shared__ float pooled[256];
  float invc = 1.0f / fmaxf((float)cnt_g[g], 1.0f);
  pooled[tid] = gsum[g*256 + tid] * invc;
  __syncthreads();
  int jl = tid >> 2, ks = tid & 3;
  int j = j0 + jl;
  const float* wrow;
  float bias;
  if (j < 512) { wrow = wf + (size_t)j*256;        bias = bf[j]; }
  else         { wrow = wb + (size_t)(j-512)*256;  bias = bb[j-512]; }
  const float4* w4 = (const float4*)(wrow + ks*64);
  const float4* p4 = (const float4*)(&pooled[ks*64]);
  float acc = 0.f;
  #pragma unroll
  for (int i = 0; i < 16; i++) {
    float4 a = w4[i], b = p4[i];
    acc += a.x*b.x + a.y*b.y + a.z*b.z + a.w*b.w;
  }
  acc += __shfl_xor(acc, 1, 64);
  acc += __shfl_xor(acc, 2, 64);
  if (ks == 0) gates[(size_t)g*1024 + j] = acc + bias;
}

// LSTM nonlinearity (T=1, zero state) + FC strip of 125 columns.
// grid (4, 64): block (cx, g) -> logits[g][cx*125 .. +124]
__global__ __launch_bounds__(256) void k_lstmfc(
    const float* __restrict__ gates, const float* __restrict__ fw,
    const float* __restrict__ fb, float* __restrict__ logits) {
  int g = blockIdx.y;
  int c0 = blockIdx.x * 125;
  int tid = threadIdx.x;
  __shared__ float gg[1024];
  __shared__ float lstm[256];
  __shared__ float sred[256];
  #pragma unroll
  for (int u = 0; u < 4; u++) gg[tid + u*256] = gates[(size_t)g*1024 + tid + u*256];
  __syncthreads();
  if (tid < 128) {
    float i = gg[tid], z = gg[256+tid], o = gg[384+tid];
    float cc = sigm(i)*tanhf(z);
    lstm[tid] = sigm(o)*tanhf(cc);
  } else {
    int u = tid - 128;
    float i = gg[512+u], z = gg[768+u], o = gg[896+u];
    float cc = sigm(i)*tanhf(z);
    lstm[128+u] = sigm(o)*tanhf(cc);
  }
  __syncthreads();
  int kh = tid >> 7;       // 0: k=[0,128), 1: k=[128,256)
  int cl = tid & 127;      // column within strip (use < 125)
  float acc = 0.f;
  if (cl < 125) {
    const float* fcol = fw + (size_t)kh*128*500 + (c0 + cl);
    #pragma unroll 8
    for (int k = 0; k < 128; k++)
      acc += lstm[kh*128 + k] * fcol[(size_t)k*500];
  }
  sred[tid] = acc;
  __syncthreads();
  if (tid < 125)
    logits[(size_t)g*500 + c0 + tid] = sred[tid] + sred[tid+128] + fb[c0 + tid];
}

// log_softmax over 500 logits per graph
__global__ __launch_bounds__(256) void k_smax(
    const float* __restrict__ logits, float* __restrict__ out) {
  int g = blockIdx.x, tid = threadIdx.x;
  __shared__ float sred[256];
  float l0 = logits[(size_t)g*500 + tid];
  float l1 = (tid < 244) ? logits[(size_t)g*500 + 256 + tid] : -1e30f;
  float m = fmaxf(l0, l1);
  sred[tid] = m; __syncthreads();
  for (int d = 128; d > 0; d >>= 1) {
    if (tid < d) sred[tid] = fmaxf(sred[tid], sred[tid+d]);
    __syncthreads();
  }
  float mx = sred[0]; __syncthreads();
  float s = expf(l0 - mx) + ((tid < 244) ? expf(l1 - mx) : 0.f);
  sred[tid] = s; __syncthreads();
  for (int d = 128; d > 0; d >>= 1) {
    if (tid < d) sred[tid] += sred[tid+d];
    __syncthreads();
  }
  float lse = logf(sred[0]) + mx;
  out[(size_t)g*500 + tid] = l0 - lse;
  if (tid < 244) out[(size_t)g*500 + 256 + tid] = l1 - lse;
}

extern "C" void kernel_launch(void* const* d_in, const int* in_sizes, int n_in,
                              void* d_out, int out_size, void* d_ws, size_t ws_size,
                              hipStream_t stream) {
  const float* x     = (const float*)d_in[0];
  const int*   ei    = (const int*)d_in[1];
  const int*   batch = (const int*)d_in[2];
  const float* W1 = (const float*)d_in[3];  const float* b1 = (const float*)d_in[4];
  const float* W2 = (const float*)d_in[5];  const float* b2 = (const float*)d_in[6];
  const float* W3 = (const float*)d_in[7];  const float* b3 = (const float*)d_in[8];
  const float* wf = (const float*)d_in[9];  const float* bf = (const float*)d_in[11];
  const float* wb = (const float*)d_in[12]; const float* bb = (const float*)d_in[14];
  const float* fw = (const float*)d_in[15]; const float* fb = (const float*)d_in[16];
  int N = in_sizes[2];
  int E = in_sizes[1] / 2;
  const int* src = ei;
  const int* dst = ei + E;

  char* w = (char*)d_ws;
  auto alloc = [&](size_t bytes) { char* p = w; w += (bytes + 255) / 256 * 256; return p; };
  int*   icnt   = (int*)  alloc((size_t)N*4);
  int*   fill   = (int*)  alloc((size_t)N*4);
  int*   cnt_g  = (int*)  alloc(NG*4);
  int*   cursor = (int*)  alloc(256);
  float* gsum   = (float*)alloc(NG*256*4);
  char*  zero_end = w;
  int*   offs  = (int*)  alloc((size_t)N*4);
  float* dinv  = (float*)alloc((size_t)N*4);
  float* selfn = (float*)alloc((size_t)N*4);
  int*   col   = (int*)  alloc((size_t)E*4);
  float* wgt   = (float*)alloc((size_t)E*4);
  float* B0    = (float*)alloc((size_t)N*128*4);
  float* B1    = (float*)alloc((size_t)N*128*4);
  float* gates  = (float*)alloc((size_t)NG*1024*4);
  float* logits = (float*)alloc((size_t)NG*500*4);

  long zwords = (zero_end - (char*)icnt) / 4;
  k_zero<<<256, 256, 0, stream>>>(icnt, zwords);
  k_hist<<<CDIV(E,256), 256, 0, stream>>>(dst, icnt, E);
  k_node<<<CDIV(N,256), 256, 0, stream>>>(icnt, batch, dinv, selfn, offs, cursor, cnt_g, N);
  k_fill<<<CDIV(E,256), 256, 0, stream>>>(src, dst, dinv, offs, fill, col, wgt, E);

  // layer 1: y1 = x @ W1 (N x 64), then gather at F=64 with bias+relu -> h1
  k_gemm<128,0><<<dim3(CDIV(N,64),1), 256, 0, stream>>>(x, W1, nullptr, B0, N, 64, nullptr, nullptr);
  k_gather<64,true><<<CDIV(N,4), 256, 0, stream>>>(B0, B1, col, wgt, offs, icnt, selfn, b1, N);
  // layer 2: gather at F=64 -> z2, then h2 = relu(z2 @ W2 + b2) (N x 128)
  k_gather<64,false><<<CDIV(N,4), 256, 0, stream>>>(B1, B0, col, wgt, offs, icnt, selfn, nullptr, N);
  k_gemm<64,1><<<dim3(CDIV(N,64),2), 256, 0, stream>>>(B0, W2, b2, B1, N, 128, nullptr, nullptr);
  // layer 3: gather at F=128 -> z3, then fused relu(z3 @ W3 + b3) + graph-sum pooling
  k_gather<128,false><<<CDIV(N,4), 256, 0, stream>>>(B1, B0, col, wgt, offs, icnt, selfn, nullptr, N);
  k_gemm<128,2><<<dim3(CDIV(N,64),4), 256, 0, stream>>>(B0, W3, b3, nullptr, N, 256, batch, gsum);
  // head: gates GEMV (high parallelism) -> LSTM+FC strips -> log_softmax
  k_gates<<<dim3(16, NG), 256, 0, stream>>>(gsum, cnt_g, wf, bf, wb, bb, gates);
  k_lstmfc<<<dim3(4, NG), 256, 0, stream>>>(gates, fw, fb, logits);
  k_smax<<<NG, 256, 0, stream>>>(logits, (float*)d_out);
}

// Round 5
// 469.981 us; speedup vs baseline: 3.4280x; 1.2381x over previous
//
#include <hip/hip_runtime.h>
#include <cstdint>
#include <cstddef>

#define CDIV(a,b) (((a)+(b)-1)/(b))
constexpr int NG = 64;

typedef _Float16 h2 __attribute__((ext_vector_type(2)));
typedef _Float16 h4 __attribute__((ext_vector_type(4)));
typedef _Float16 h8 __attribute__((ext_vector_type(8)));

__global__ void k_zero(int* p, long n) {
  long i = (long)blockIdx.x*blockDim.x + threadIdx.x;
  long stride = (long)gridDim.x*blockDim.x;
  for (; i < n; i += stride) p[i] = 0;
}

__global__ void k_hist(const int* __restrict__ dst, int* __restrict__ icnt, int E) {
  int e = blockIdx.x*blockDim.x + threadIdx.x;
  if (e < E) atomicAdd(&icnt[dst[e]], 1);
}

// per-node: dinv, selfnorm, CSR offsets (block scan + one atomic per block), graph histogram
__global__ void k_node(const int* __restrict__ icnt, const int* __restrict__ batch,
                       float* __restrict__ dinv, float* __restrict__ selfn,
                       int* __restrict__ offs, int* __restrict__ cursor,
                       int* __restrict__ cnt_g, int n) {
  __shared__ int scan[256];
  __shared__ int hist[NG];
  __shared__ int base;
  int tid = threadIdx.x;
  int i = blockIdx.x*256 + tid;
  if (tid < NG) hist[tid] = 0;
  int c = (i < n) ? icnt[i] : 0;
  scan[tid] = c;
  __syncthreads();
  for (int d = 1; d < 256; d <<= 1) {
    int t = (tid >= d) ? scan[tid-d] : 0;
    __syncthreads();
    scan[tid] += t;
    __syncthreads();
  }
  if (tid == 255) base = atomicAdd(cursor, scan[255]);
  __syncthreads();
  if (i < n) {
    offs[i] = base + scan[tid] - c;
    float deg = (float)(c + 1);
    dinv[i] = rsqrtf(deg);
    selfn[i] = 1.0f / deg;
    atomicAdd(&hist[batch[i]], 1);
  }
  __syncthreads();
  if (tid < NG && hist[tid]) atomicAdd(&cnt_g[tid], hist[tid]);
}

// packed edge record: .x = src index, .y = weight bits
__global__ void k_fill(const int* __restrict__ src, const int* __restrict__ dst,
                       const float* __restrict__ dinv, const int* __restrict__ offs,
                       int* __restrict__ fill, int2* __restrict__ ew, int E) {
  int e = blockIdx.x*blockDim.x + threadIdx.x;
  if (e >= E) return;
  int s = src[e], d = dst[e];
  int p = offs[d] + atomicAdd(&fill[d], 1);
  ew[p] = make_int2(s, __float_as_int(dinv[s] * dinv[d]));
}

// fp16 gather: z[i] = sum_e w_e * y[src_e] + selfn[i]*y[i]  (+bias,relu for L1)
// F=128: 1 node/wave (64 lanes x half2). F=64: 2 nodes/wave (32 lanes x half2).
template<int F, bool L1>
__global__ __launch_bounds__(256) void k_gather_h(
    const _Float16* __restrict__ y, _Float16* __restrict__ z,
    const int2* __restrict__ ew, const int* __restrict__ offs,
    const int* __restrict__ icnt, const float* __restrict__ selfn,
    const float* __restrict__ bias, int n) {
  constexpr int LPN = F / 2;     // lanes per node
  constexpr int NPW = 64 / LPN;  // nodes per wave
  int wid = (int)((blockIdx.x*(size_t)blockDim.x + threadIdx.x) >> 6);
  int lane = threadIdx.x & 63;
  int sub = lane / LPN;
  int li  = lane % LPN;
  int gw = wid * NPW + sub;
  if (gw >= n) return;
  float sn = selfn[gw];
  h2 sv = *(const h2*)(y + (size_t)gw*F + li*2);
  float a0 = (float)sv.x * sn, a1 = (float)sv.y * sn;
  int e = offs[gw], eend = e + icnt[gw];
  for (; e + 7 < eend; e += 8) {
    int2 c[8];
    #pragma unroll
    for (int u = 0; u < 8; u++) c[u] = ew[e + u];
    #pragma unroll
    for (int u = 0; u < 8; u++) {
      h2 v = *(const h2*)(y + (size_t)c[u].x*F + li*2);
      float w = __int_as_float(c[u].y);
      a0 += (float)v.x * w;
      a1 += (float)v.y * w;
    }
  }
  for (; e < eend; e++) {
    int2 cu = ew[e];
    h2 v = *(const h2*)(y + (size_t)cu.x*F + li*2);
    float w = __int_as_float(cu.y);
    a0 += (float)v.x * w;
    a1 += (float)v.y * w;
  }
  if constexpr (L1) {
    a0 += bias[li*2];   a0 = fmaxf(a0, 0.f);
    a1 += bias[li*2+1]; a1 = fmaxf(a1, 0.f);
  }
  h2 o; o.x = (_Float16)a0; o.y = (_Float16)a1;
  *(h2*)(z + (size_t)gw*F + li*2) = o;
}

// C[n x nout] = A[n x K] @ W[K x nout], BM=BN=64, TM=TN=4, 256 threads, KC=32.
// AH: A is fp16. OH: C stored fp16 (EPI<=1 only).
// EPI: 0=plain store, 1=bias+relu store, 2=bias+relu + fused graph-pool (no store)
template<int K, int EPI, bool AH, bool OH>
__global__ __launch_bounds__(256, 4) void k_gemm(
    const void* __restrict__ Av, const float* __restrict__ W,
    const float* __restrict__ bias, void* __restrict__ Cv,
    int n, int nout, const int* __restrict__ batch, float* __restrict__ gsum) {
  constexpr int BM = 64, BN = 64, KC = 32;
  __shared__ float sA[BM][KC + 4];
  __shared__ float sW[KC][BN];
  __shared__ float red[16][BN];
  int row0 = blockIdx.x * BM, col0 = blockIdx.y * BN;
  int tid = threadIdx.x;
  int tx = tid & 15, ty = tid >> 4;
  float acc[4][4] = {};

  int lw_k  = tid >> 4;
  int lw_c4 = tid & 15;

  for (int kc = 0; kc < K; kc += KC) {
    if constexpr (AH) {
      const _Float16* A = (const _Float16*)Av;
      int r = tid >> 2, c8 = (tid & 3) * 8;
      int row = row0 + r;
      h8 v = {};
      if (row < n) v = *(const h8*)(A + (size_t)row*K + kc + c8);
      #pragma unroll
      for (int u = 0; u < 8; u++) sA[r][c8 + u] = (float)v[u];
    } else {
      const float* A = (const float*)Av;
      int la_r = tid >> 3, la_c4 = tid & 7;
      #pragma unroll
      for (int rr = 0; rr < BM; rr += 32) {
        int row = row0 + la_r + rr;
        float4 v = (row < n) ? *(const float4*)&A[(size_t)row*K + kc + la_c4*4]
                             : make_float4(0.f, 0.f, 0.f, 0.f);
        *(float4*)&sA[la_r + rr][la_c4*4] = v;
      }
    }
    #pragma unroll
    for (int kk = 0; kk < KC; kk += 16) {
      float4 v = *(const float4*)&W[(size_t)(kc + lw_k + kk)*nout + col0 + lw_c4*4];
      *(float4*)&sW[lw_k + kk][lw_c4*4] = v;
    }
    __syncthreads();

    #pragma unroll 1
    for (int k = 0; k < KC; k += 4) {
      float4 av[4], wv[4];
      #pragma unroll
      for (int r = 0; r < 4; r++) av[r] = *(const float4*)&sA[ty*4 + r][k];
      #pragma unroll
      for (int j = 0; j < 4; j++) wv[j] = *(const float4*)&sW[k + j][tx*4];
      #pragma unroll
      for (int j = 0; j < 4; j++) {
        float4 wj = wv[j];
        #pragma unroll
        for (int r = 0; r < 4; r++) {
          float aj = (j == 0) ? av[r].x : (j == 1) ? av[r].y : (j == 2) ? av[r].z : av[r].w;
          acc[r][0] += aj * wj.x;
          acc[r][1] += aj * wj.y;
          acc[r][2] += aj * wj.z;
          acc[r][3] += aj * wj.w;
        }
      }
    }
    __syncthreads();
  }

  if constexpr (EPI >= 1) {
    float bv[4];
    #pragma unroll
    for (int c2 = 0; c2 < 4; c2++) bv[c2] = bias[col0 + tx*4 + c2];
    #pragma unroll
    for (int r = 0; r < 4; r++)
      #pragma unroll
      for (int c2 = 0; c2 < 4; c2++)
        acc[r][c2] = fmaxf(acc[r][c2] + bv[c2], 0.f);
  }
  if constexpr (EPI <= 1) {
    #pragma unroll
    for (int r = 0; r < 4; r++) {
      int row = row0 + ty*4 + r;
      if (row < n) {
        if constexpr (OH) {
          _Float16* C = (_Float16*)Cv;
          h4 o;
          o.x = (_Float16)acc[r][0]; o.y = (_Float16)acc[r][1];
          o.z = (_Float16)acc[r][2]; o.w = (_Float16)acc[r][3];
          *(h4*)&C[(size_t)row*nout + col0 + tx*4] = o;
        } else {
          float* C = (float*)Cv;
          *(float4*)&C[(size_t)row*nout + col0 + tx*4] =
              make_float4(acc[r][0], acc[r][1], acc[r][2], acc[r][3]);
        }
      }
    }
  } else {
    int g0 = batch[row0];
    int g1 = batch[min(row0 + BM - 1, n - 1)];
    for (int g = g0; g <= g1; ++g) {
      float p0 = 0, p1 = 0, p2 = 0, p3 = 0;
      #pragma unroll
      for (int r = 0; r < 4; r++) {
        int row = row0 + ty*4 + r;
        if (row < n && batch[row] == g) {
          p0 += acc[r][0]; p1 += acc[r][1]; p2 += acc[r][2]; p3 += acc[r][3];
        }
      }
      red[ty][tx*4+0] = p0; red[ty][tx*4+1] = p1;
      red[ty][tx*4+2] = p2; red[ty][tx*4+3] = p3;
      __syncthreads();
      if (tid < BN) {
        float s = 0;
        #pragma unroll
        for (int j = 0; j < 16; j++) s += red[j][tid];
        atomicAdd(&gsum[g*256 + col0 + tid], s);
      }
      __syncthreads();
    }
  }
}

__device__ __forceinline__ float sigm(float x) { return 1.f / (1.f + expf(-x)); }

// gates[g][j] for j in [0,1024): [0,512)=forward, [512,1024)=backward.
__global__ __launch_bounds__(256) void k_gates(
    const float* __restrict__ gsum, const int* __restrict__ cnt_g,
    const float* __restrict__ wf, const float* __restrict__ bf,
    const float* __restrict__ wb, const float* __restrict__ bb,
    float* __restrict__ gates) {
  int g = blockIdx.y;
  int j0 = blockIdx.x * 64;
  int tid = threadIdx.x;
  __shared__ float pooled[256];
  float invc = 1.0f / fmaxf((float)cnt_g[g], 1.0f);
  pooled[tid] = gsum[g*256 + tid] * invc;
  __syncthreads();
  int jl = tid >> 2, ks = tid & 3;
  int j = j0 + jl;
  const float* wrow;
  float bias;
  if (j < 512) { wrow = wf + (size_t)j*256;        bias = bf[j]; }
  else         { wrow = wb + (size_t)(j-512)*256;  bias = bb[j-512]; }
  const float4* w4 = (const float4*)(wrow + ks*64);
  const float4* p4 = (const float4*)(&pooled[ks*64]);
  float acc = 0.f;
  #pragma unroll
  for (int i = 0; i < 16; i++) {
    float4 a = w4[i], b = p4[i];
    acc += a.x*b.x + a.y*b.y + a.z*b.z + a.w*b.w;
  }
  acc += __shfl_xor(acc, 1, 64);
  acc += __shfl_xor(acc, 2, 64);
  if (ks == 0) gates[(size_t)g*1024 + j] = acc + bias;
}

// LSTM nonlinearity (T=1, zero state) + FC strip of 125 columns.
__global__ __launch_bounds__(256) void k_lstmfc(
    const float* __restrict__ gates, const float* __restrict__ fw,
    const float* __restrict__ fb, float* __restrict__ logits) {
  int g = blockIdx.y;
  int c0 = blockIdx.x * 125;
  int tid = threadIdx.x;
  __shared__ float gg[1024];
  __shared__ float lstm[256];
  __shared__ float sred[256];
  #pragma unroll
  for (int u = 0; u < 4; u++) gg[tid + u*256] = gates[(size_t)g*1024 + tid + u*256];
  __syncthreads();
  if (tid < 128) {
    float i = gg[tid], z = gg[256+tid], o = gg[384+tid];
    float cc = sigm(i)*tanhf(z);
    lstm[tid] = sigm(o)*tanhf(cc);
  } else {
    int u = tid - 128;
    float i = gg[512+u], z = gg[768+u], o = gg[896+u];
    float cc = sigm(i)*tanhf(z);
    lstm[128+u] = sigm(o)*tanhf(cc);
  }
  __syncthreads();
  int kh = tid >> 7;
  int cl = tid & 127;
  float acc = 0.f;
  if (cl < 125) {
    const float* fcol = fw + (size_t)kh*128*500 + (c0 + cl);
    #pragma unroll 8
    for (int k = 0; k < 128; k++)
      acc += lstm[kh*128 + k] * fcol[(size_t)k*500];
  }
  sred[tid] = acc;
  __syncthreads();
  if (tid < 125)
    logits[(size_t)g*500 + c0 + tid] = sred[tid] + sred[tid+128] + fb[c0 + tid];
}

// log_softmax over 500 logits per graph
__global__ __launch_bounds__(256) void k_smax(
    const float* __restrict__ logits, float* __restrict__ out) {
  int g = blockIdx.x, tid = threadIdx.x;
  __shared__ float sred[256];
  float l0 = logits[(size_t)g*500 + tid];
  float l1 = (tid < 244) ? logits[(size_t)g*500 + 256 + tid] : -1e30f;
  float m = fmaxf(l0, l1);
  sred[tid] = m; __syncthreads();
  for (int d = 128; d > 0; d >>= 1) {
    if (tid < d) sred[tid] = fmaxf(sred[tid], sred[tid+d]);
    __syncthreads();
  }
  float mx = sred[0]; __syncthreads();
  float s = expf(l0 - mx) + ((tid < 244) ? expf(l1 - mx) : 0.f);
  sred[tid] = s; __syncthreads();
  for (int d = 128; d > 0; d >>= 1) {
    if (tid < d) sred[tid] += sred[tid+d];
    __syncthreads();
  }
  float lse = logf(sred[0]) + mx;
  out[(size_t)g*500 + tid] = l0 - lse;
  if (tid < 244) out[(size_t)g*500 + 256 + tid] = l1 - lse;
}

extern "C" void kernel_launch(void* const* d_in, const int* in_sizes, int n_in,
                              void* d_out, int out_size, void* d_ws, size_t ws_size,
                              hipStream_t stream) {
  const float* x     = (const float*)d_in[0];
  const int*   ei    = (const int*)d_in[1];
  const int*   batch = (const int*)d_in[2];
  const float* W1 = (const float*)d_in[3];  const float* b1 = (const float*)d_in[4];
  const float* W2 = (const float*)d_in[5];  const float* b2 = (const float*)d_in[6];
  const float* W3 = (const float*)d_in[7];  const float* b3 = (const float*)d_in[8];
  const float* wf = (const float*)d_in[9];  const float* bf = (const float*)d_in[11];
  const float* wb = (const float*)d_in[12]; const float* bb = (const float*)d_in[14];
  const float* fw = (const float*)d_in[15]; const float* fb = (const float*)d_in[16];
  int N = in_sizes[2];
  int E = in_sizes[1] / 2;
  const int* src = ei;
  const int* dst = ei + E;

  char* w = (char*)d_ws;
  auto alloc = [&](size_t bytes) { char* p = w; w += (bytes + 255) / 256 * 256; return p; };
  int*   icnt   = (int*)  alloc((size_t)N*4);
  int*   fill   = (int*)  alloc((size_t)N*4);
  int*   cnt_g  = (int*)  alloc(NG*4);
  int*   cursor = (int*)  alloc(256);
  float* gsum   = (float*)alloc(NG*256*4);
  char*  zero_end = w;
  int*   offs  = (int*)  alloc((size_t)N*4);
  float* dinv  = (float*)alloc((size_t)N*4);
  float* selfn = (float*)alloc((size_t)N*4);
  int2*  ew    = (int2*) alloc((size_t)E*8);
  _Float16* B0h = (_Float16*)alloc((size_t)N*128*2);
  _Float16* B1h = (_Float16*)alloc((size_t)N*128*2);
  float* gates  = (float*)alloc((size_t)NG*1024*4);
  float* logits = (float*)alloc((size_t)NG*500*4);

  long zwords = (zero_end - (char*)icnt) / 4;
  k_zero<<<256, 256, 0, stream>>>(icnt, zwords);
  k_hist<<<CDIV(E,256), 256, 0, stream>>>(dst, icnt, E);
  k_node<<<CDIV(N,256), 256, 0, stream>>>(icnt, batch, dinv, selfn, offs, cursor, cnt_g, N);
  k_fill<<<CDIV(E,256), 256, 0, stream>>>(src, dst, dinv, offs, fill, ew, E);

  // layer 1: y1 = x @ W1 (fp16), gather at F=64 with bias+relu -> h1 (fp16)
  k_gemm<128,0,false,true><<<dim3(CDIV(N,64),1), 256, 0, stream>>>(x, W1, nullptr, B0h, N, 64, nullptr, nullptr);
  k_gather_h<64,true><<<CDIV(N,8), 256, 0, stream>>>(B0h, B1h, ew, offs, icnt, selfn, b1, N);
  // layer 2: gather at F=64 -> z2 (fp16), h2 = relu(z2 @ W2 + b2) (fp16)
  k_gather_h<64,false><<<CDIV(N,8), 256, 0, stream>>>(B1h, B0h, ew, offs, icnt, selfn, nullptr, N);
  k_gemm<64,1,true,true><<<dim3(CDIV(N,64),2), 256, 0, stream>>>(B0h, W2, b2, B1h, N, 128, nullptr, nullptr);
  // layer 3: gather at F=128 -> z3 (fp16), fused relu(z3 @ W3 + b3) + graph pooling
  k_gather_h<128,false><<<CDIV(N,4), 256, 0, stream>>>(B1h, B0h, ew, offs, icnt, selfn, nullptr, N);
  k_gemm<128,2,true,false><<<dim3(CDIV(N,64),4), 256, 0, stream>>>(B0h, W3, b3, nullptr, N, 256, batch, gsum);
  // head
  k_gates<<<dim3(16, NG), 256, 0, stream>>>(gsum, cnt_g, wf, bf, wb, bb, gates);
  k_lstmfc<<<dim3(4, NG), 256, 0, stream>>>(gates, fw, fb, logits);
  k_smax<<<NG, 256, 0, stream>>>(logits, (float*)d_out);
}

// Round 6
// 392.498 us; speedup vs baseline: 4.1047x; 1.1974x over previous
//
#include <hip/hip_runtime.h>
#include <cstdint>
#include <cstddef>

#define CDIV(a,b) (((a)+(b)-1)/(b))
constexpr int NG = 64;

typedef _Float16 h2 __attribute__((ext_vector_type(2)));
typedef _Float16 h4 __attribute__((ext_vector_type(4)));
typedef _Float16 h8 __attribute__((ext_vector_type(8)));
typedef float f4 __attribute__((ext_vector_type(4)));

__global__ void k_zero(int* p, long n) {
  long i = (long)blockIdx.x*blockDim.x + threadIdx.x;
  long stride = (long)gridDim.x*blockDim.x;
  for (; i < n; i += stride) p[i] = 0;
}

__global__ void k_hist(const int* __restrict__ dst, int* __restrict__ icnt, int E) {
  int e = blockIdx.x*blockDim.x + threadIdx.x;
  if (e < E) atomicAdd(&icnt[dst[e]], 1);
}

// per-node: dinv, selfnorm, CSR offsets (block scan + one atomic per block), graph histogram
__global__ void k_node(const int* __restrict__ icnt, const int* __restrict__ batch,
                       float* __restrict__ dinv, float* __restrict__ selfn,
                       int* __restrict__ offs, int* __restrict__ cursor,
                       int* __restrict__ cnt_g, int n) {
  __shared__ int scan[256];
  __shared__ int hist[NG];
  __shared__ int base;
  int tid = threadIdx.x;
  int i = blockIdx.x*256 + tid;
  if (tid < NG) hist[tid] = 0;
  int c = (i < n) ? icnt[i] : 0;
  scan[tid] = c;
  __syncthreads();
  for (int d = 1; d < 256; d <<= 1) {
    int t = (tid >= d) ? scan[tid-d] : 0;
    __syncthreads();
    scan[tid] += t;
    __syncthreads();
  }
  if (tid == 255) base = atomicAdd(cursor, scan[255]);
  __syncthreads();
  if (i < n) {
    offs[i] = base + scan[tid] - c;
    float deg = (float)(c + 1);
    dinv[i] = rsqrtf(deg);
    selfn[i] = 1.0f / deg;
    atomicAdd(&hist[batch[i]], 1);
  }
  __syncthreads();
  if (tid < NG && hist[tid]) atomicAdd(&cnt_g[tid], hist[tid]);
}

// packed edge record: .x = src index, .y = weight bits
__global__ void k_fill(const int* __restrict__ src, const int* __restrict__ dst,
                       const float* __restrict__ dinv, const int* __restrict__ offs,
                       int* __restrict__ fill, int2* __restrict__ ew, int E) {
  int e = blockIdx.x*blockDim.x + threadIdx.x;
  if (e >= E) return;
  int s = src[e], d = dst[e];
  int p = offs[d] + atomicAdd(&fill[d], 1);
  ew[p] = make_int2(s, __float_as_int(dinv[s] * dinv[d]));
}

// W[K x nout] fp32 -> WT[nout x K] fp16
__global__ void k_wcvt(const float* __restrict__ W, _Float16* __restrict__ WT,
                       int K, int nout) {
  int idx = blockIdx.x*256 + threadIdx.x;
  if (idx >= K*nout) return;
  int c = idx / K, k = idx % K;
  WT[idx] = (_Float16)W[(size_t)k*nout + c];
}

// fp16 gather: z[i] = sum_e w_e * y[src_e] + selfn[i]*y[i]  (+bias,relu for L1)
template<int F, bool L1>
__global__ __launch_bounds__(256) void k_gather_h(
    const _Float16* __restrict__ y, _Float16* __restrict__ z,
    const int2* __restrict__ ew, const int* __restrict__ offs,
    const int* __restrict__ icnt, const float* __restrict__ selfn,
    const float* __restrict__ bias, int n) {
  constexpr int LPN = F / 2;
  constexpr int NPW = 64 / LPN;
  int wid = (int)((blockIdx.x*(size_t)blockDim.x + threadIdx.x) >> 6);
  int lane = threadIdx.x & 63;
  int sub = lane / LPN;
  int li  = lane % LPN;
  int gw = wid * NPW + sub;
  if (gw >= n) return;
  float sn = selfn[gw];
  h2 sv = *(const h2*)(y + (size_t)gw*F + li*2);
  float a0 = (float)sv.x * sn, a1 = (float)sv.y * sn;
  int e = offs[gw], eend = e + icnt[gw];
  for (; e + 7 < eend; e += 8) {
    int2 c[8];
    #pragma unroll
    for (int u = 0; u < 8; u++) c[u] = ew[e + u];
    #pragma unroll
    for (int u = 0; u < 8; u++) {
      h2 v = *(const h2*)(y + (size_t)c[u].x*F + li*2);
      float w = __int_as_float(c[u].y);
      a0 += (float)v.x * w;
      a1 += (float)v.y * w;
    }
  }
  for (; e < eend; e++) {
    int2 cu = ew[e];
    h2 v = *(const h2*)(y + (size_t)cu.x*F + li*2);
    float w = __int_as_float(cu.y);
    a0 += (float)v.x * w;
    a1 += (float)v.y * w;
  }
  if constexpr (L1) {
    a0 += bias[li*2];   a0 = fmaxf(a0, 0.f);
    a1 += bias[li*2+1]; a1 = fmaxf(a1, 0.f);
  }
  h2 o; o.x = (_Float16)a0; o.y = (_Float16)a1;
  *(h2*)(z + (size_t)gw*F + li*2) = o;
}

// MFMA GEMM: C[n x NOUT] = A[n x K] @ W, NOUT = CF*64, block = 64 rows x NOUT.
// 4 waves; wave w owns cols [w*CF*16, (w+1)*CF*16). B frags (from WT fp16) in regs.
// EPI: 0=plain fp16 store, 1=bias+relu fp16 store, 2=bias+relu + fused graph pool
// AF32: A is fp32 (converted to fp16 during staging)
template<int K, int CF, int EPI, bool AF32>
__global__ __launch_bounds__(256, 2) void k_mgemm(
    const void* __restrict__ Av, const _Float16* __restrict__ WT,
    const float* __restrict__ bias, _Float16* __restrict__ C,
    int n, const int* __restrict__ batch, float* __restrict__ gsum) {
  constexpr int KS = K / 32;
  constexpr int NOUT = CF * 64;
  constexpr int LDA = K + 8;                 // +16B pad: frag reads are 2-way (free)
  __shared__ __align__(16) _Float16 sA[64][LDA];
  __shared__ float red[4][256];
  __shared__ int sBatch[64];
  int tid = threadIdx.x;
  int row0 = blockIdx.x * 64;
  int lane = tid & 63, wv = tid >> 6;
  int grp = lane >> 4, l16 = lane & 15;
  int wcol0 = wv * (CF * 16);

  // ---- stage A tile (64 x K) into LDS as fp16 ----
  {
    int srow = tid >> 2;
    bool ok = (row0 + srow) < n;
    if constexpr (AF32) {
      const float* A = (const float*)Av;
      #pragma unroll
      for (int u = 0; u < K/16; u++) {
        int c4 = (tid & 3) + 4*u;
        float4 v = ok ? *(const float4*)(A + (size_t)(row0+srow)*K + c4*4)
                      : make_float4(0.f,0.f,0.f,0.f);
        h4 o; o.x=(_Float16)v.x; o.y=(_Float16)v.y; o.z=(_Float16)v.z; o.w=(_Float16)v.w;
        *(h4*)&sA[srow][c4*4] = o;
      }
    } else {
      const _Float16* A = (const _Float16*)Av;
      #pragma unroll
      for (int u = 0; u < K/32; u++) {
        int c8 = (tid & 3) + 4*u;
        h8 v = {};
        if (ok) v = *(const h8*)(A + (size_t)(row0+srow)*K + c8*8);
        *(h8*)&sA[srow][c8*8] = v;
      }
    }
  }
  if constexpr (EPI == 2) {
    if (tid < 64) sBatch[tid] = (row0 + tid < n) ? batch[row0 + tid] : -1;
  }

  // ---- B fragments: held in registers across whole K loop (W is L2-hot) ----
  h8 bfrag[KS][CF];
  #pragma unroll
  for (int ks = 0; ks < KS; ks++)
    #pragma unroll
    for (int cf = 0; cf < CF; cf++) {
      int col = wcol0 + cf*16 + l16;
      bfrag[ks][cf] = *(const h8*)(WT + (size_t)col*K + ks*32 + grp*8);
    }

  f4 acc[4][CF] = {};
  __syncthreads();

  // ---- MFMA K loop ----
  #pragma unroll
  for (int ks = 0; ks < KS; ks++) {
    h8 af[4];
    #pragma unroll
    for (int rf = 0; rf < 4; rf++)
      af[rf] = *(const h8*)&sA[rf*16 + l16][ks*32 + grp*8];
    #pragma unroll
    for (int rf = 0; rf < 4; rf++)
      #pragma unroll
      for (int cf = 0; cf < CF; cf++)
        acc[rf][cf] = __builtin_amdgcn_mfma_f32_16x16x32_f16(
            af[rf], bfrag[ks][cf], acc[rf][cf], 0, 0, 0);
  }

  // ---- epilogue ----
  if constexpr (EPI <= 1) {
    #pragma unroll
    for (int rf = 0; rf < 4; rf++) {
      #pragma unroll
      for (int r = 0; r < 4; r++) {
        int row = row0 + rf*16 + grp*4 + r;
        if (row < n) {
          #pragma unroll
          for (int cf = 0; cf < CF; cf++) {
            int col = wcol0 + cf*16 + l16;
            float v = acc[rf][cf][r];
            if constexpr (EPI == 1) v = fmaxf(v + bias[col], 0.f);
            C[(size_t)row*NOUT + col] = (_Float16)v;
          }
        }
      }
    }
  } else {
    // bias + relu in-register
    float bv[CF];
    #pragma unroll
    for (int cf = 0; cf < CF; cf++) bv[cf] = bias[wcol0 + cf*16 + l16];
    #pragma unroll
    for (int rf = 0; rf < 4; rf++)
      #pragma unroll
      for (int cf = 0; cf < CF; cf++)
        #pragma unroll
        for (int r = 0; r < 4; r++)
          acc[rf][cf][r] = fmaxf(acc[rf][cf][r] + bv[cf], 0.f);
    __syncthreads();
    int g0 = sBatch[0];
    int g1 = batch[min(row0 + 63, n - 1)];
    for (int g = g0; g <= g1; ++g) {
      float p[CF] = {};
      #pragma unroll
      for (int rf = 0; rf < 4; rf++)
        #pragma unroll
        for (int r = 0; r < 4; r++) {
          int lrow = rf*16 + grp*4 + r;
          bool m = (sBatch[lrow] == g);
          #pragma unroll
          for (int cf = 0; cf < CF; cf++)
            if (m) p[cf] += acc[rf][cf][r];
        }
      #pragma unroll
      for (int cf = 0; cf < CF; cf++)
        red[grp][wcol0 + cf*16 + l16] = p[cf];
      __syncthreads();
      if (tid < NOUT) {
        float s = red[0][tid] + red[1][tid] + red[2][tid] + red[3][tid];
        atomicAdd(&gsum[g*256 + tid], s);
      }
      __syncthreads();
    }
  }
}

__device__ __forceinline__ float sigm(float x) { return 1.f / (1.f + expf(-x)); }

// gates[g][j] for j in [0,1024): [0,512)=forward, [512,1024)=backward.
__global__ __launch_bounds__(256) void k_gates(
    const float* __restrict__ gsum, const int* __restrict__ cnt_g,
    const float* __restrict__ wf, const float* __restrict__ bf,
    const float* __restrict__ wb, const float* __restrict__ bb,
    float* __restrict__ gates) {
  int g = blockIdx.y;
  int j0 = blockIdx.x * 64;
  int tid = threadIdx.x;
  __shared__ float pooled[256];
  float invc = 1.0f / fmaxf((float)cnt_g[g], 1.0f);
  pooled[tid] = gsum[g*256 + tid] * invc;
  __syncthreads();
  int jl = tid >> 2, ks = tid & 3;
  int j = j0 + jl;
  const float* wrow;
  float bias;
  if (j < 512) { wrow = wf + (size_t)j*256;        bias = bf[j]; }
  else         { wrow = wb + (size_t)(j-512)*256;  bias = bb[j-512]; }
  const float4* w4 = (const float4*)(wrow + ks*64);
  const float4* p4 = (const float4*)(&pooled[ks*64]);
  float acc = 0.f;
  #pragma unroll
  for (int i = 0; i < 16; i++) {
    float4 a = w4[i], b = p4[i];
    acc += a.x*b.x + a.y*b.y + a.z*b.z + a.w*b.w;
  }
  acc += __shfl_xor(acc, 1, 64);
  acc += __shfl_xor(acc, 2, 64);
  if (ks == 0) gates[(size_t)g*1024 + j] = acc + bias;
}

// LSTM nonlinearity (T=1, zero state) + FC strip of 125 columns.
__global__ __launch_bounds__(256) void k_lstmfc(
    const float* __restrict__ gates, const float* __restrict__ fw,
    const float* __restrict__ fb, float* __restrict__ logits) {
  int g = blockIdx.y;
  int c0 = blockIdx.x * 125;
  int tid = threadIdx.x;
  __shared__ float gg[1024];
  __shared__ float lstm[256];
  __shared__ float sred[256];
  #pragma unroll
  for (int u = 0; u < 4; u++) gg[tid + u*256] = gates[(size_t)g*1024 + tid + u*256];
  __syncthreads();
  if (tid < 128) {
    float i = gg[tid], z = gg[256+tid], o = gg[384+tid];
    float cc = sigm(i)*tanhf(z);
    lstm[tid] = sigm(o)*tanhf(cc);
  } else {
    int u = tid - 128;
    float i = gg[512+u], z = gg[768+u], o = gg[896+u];
    float cc = sigm(i)*tanhf(z);
    lstm[128+u] = sigm(o)*tanhf(cc);
  }
  __syncthreads();
  int kh = tid >> 7;
  int cl = tid & 127;
  float acc = 0.f;
  if (cl < 125) {
    const float* fcol = fw + (size_t)kh*128*500 + (c0 + cl);
    #pragma unroll 8
    for (int k = 0; k < 128; k++)
      acc += lstm[kh*128 + k] * fcol[(size_t)k*500];
  }
  sred[tid] = acc;
  __syncthreads();
  if (tid < 125)
    logits[(size_t)g*500 + c0 + tid] = sred[tid] + sred[tid+128] + fb[c0 + tid];
}

// log_softmax over 500 logits per graph
__global__ __launch_bounds__(256) void k_smax(
    const float* __restrict__ logits, float* __restrict__ out) {
  int g = blockIdx.x, tid = threadIdx.x;
  __shared__ float sred[256];
  float l0 = logits[(size_t)g*500 + tid];
  float l1 = (tid < 244) ? logits[(size_t)g*500 + 256 + tid] : -1e30f;
  float m = fmaxf(l0, l1);
  sred[tid] = m; __syncthreads();
  for (int d = 128; d > 0; d >>= 1) {
    if (tid < d) sred[tid] = fmaxf(sred[tid], sred[tid+d]);
    __syncthreads();
  }
  float mx = sred[0]; __syncthreads();
  float s = expf(l0 - mx) + ((tid < 244) ? expf(l1 - mx) : 0.f);
  sred[tid] = s; __syncthreads();
  for (int d = 128; d > 0; d >>= 1) {
    if (tid < d) sred[tid] += sred[tid+d];
    __syncthreads();
  }
  float lse = logf(sred[0]) + mx;
  out[(size_t)g*500 + tid] = l0 - lse;
  if (tid < 244) out[(size_t)g*500 + 256 + tid] = l1 - lse;
}

extern "C" void kernel_launch(void* const* d_in, const int* in_sizes, int n_in,
                              void* d_out, int out_size, void* d_ws, size_t ws_size,
                              hipStream_t stream) {
  const float* x     = (const float*)d_in[0];
  const int*   ei    = (const int*)d_in[1];
  const int*   batch = (const int*)d_in[2];
  const float* W1 = (const float*)d_in[3];  const float* b1 = (const float*)d_in[4];
  const float* W2 = (const float*)d_in[5];  const float* b2 = (const float*)d_in[6];
  const float* W3 = (const float*)d_in[7];  const float* b3 = (const float*)d_in[8];
  const float* wf = (const float*)d_in[9];  const float* bf = (const float*)d_in[11];
  const float* wb = (const float*)d_in[12]; const float* bb = (const float*)d_in[14];
  const float* fw = (const float*)d_in[15]; const float* fb = (const float*)d_in[16];
  int N = in_sizes[2];
  int E = in_sizes[1] / 2;
  const int* src = ei;
  const int* dst = ei + E;

  char* w = (char*)d_ws;
  auto alloc = [&](size_t bytes) { char* p = w; w += (bytes + 255) / 256 * 256; return p; };
  int*   icnt   = (int*)  alloc((size_t)N*4);
  int*   fill   = (int*)  alloc((size_t)N*4);
  int*   cnt_g  = (int*)  alloc(NG*4);
  int*   cursor = (int*)  alloc(256);
  float* gsum   = (float*)alloc(NG*256*4);
  char*  zero_end = w;
  int*   offs  = (int*)  alloc((size_t)N*4);
  float* dinv  = (float*)alloc((size_t)N*4);
  float* selfn = (float*)alloc((size_t)N*4);
  int2*  ew    = (int2*) alloc((size_t)E*8);
  _Float16* B0h = (_Float16*)alloc((size_t)N*128*2);
  _Float16* B1h = (_Float16*)alloc((size_t)N*128*2);
  _Float16* WT1 = (_Float16*)alloc(128*64*2);
  _Float16* WT2 = (_Float16*)alloc(64*128*2);
  _Float16* WT3 = (_Float16*)alloc(128*256*2);
  float* gates  = (float*)alloc((size_t)NG*1024*4);
  float* logits = (float*)alloc((size_t)NG*500*4);

  long zwords = (zero_end - (char*)icnt) / 4;
  k_zero<<<256, 256, 0, stream>>>(icnt, zwords);
  k_hist<<<CDIV(E,256), 256, 0, stream>>>(dst, icnt, E);
  k_node<<<CDIV(N,256), 256, 0, stream>>>(icnt, batch, dinv, selfn, offs, cursor, cnt_g, N);
  k_fill<<<CDIV(E,256), 256, 0, stream>>>(src, dst, dinv, offs, fill, ew, E);
  k_wcvt<<<CDIV(128*64,256), 256, 0, stream>>>(W1, WT1, 128, 64);
  k_wcvt<<<CDIV(64*128,256), 256, 0, stream>>>(W2, WT2, 64, 128);
  k_wcvt<<<CDIV(128*256,256), 256, 0, stream>>>(W3, WT3, 128, 256);

  // layer 1: y1 = x @ W1 (MFMA, fp32->fp16 A), gather at F=64 with bias+relu
  k_mgemm<128,1,0,true><<<CDIV(N,64), 256, 0, stream>>>(x, WT1, nullptr, B0h, N, nullptr, nullptr);
  k_gather_h<64,true><<<CDIV(N,8), 256, 0, stream>>>(B0h, B1h, ew, offs, icnt, selfn, b1, N);
  // layer 2: gather at F=64 -> z2, h2 = relu(z2 @ W2 + b2) (MFMA)
  k_gather_h<64,false><<<CDIV(N,8), 256, 0, stream>>>(B1h, B0h, ew, offs, icnt, selfn, nullptr, N);
  k_mgemm<64,2,1,false><<<CDIV(N,64), 256, 0, stream>>>(B0h, WT2, b2, B1h, N, nullptr, nullptr);
  // layer 3: gather at F=128 -> z3, fused relu(z3 @ W3 + b3) + graph pooling (MFMA)
  k_gather_h<128,false><<<CDIV(N,4), 256, 0, stream>>>(B1h, B0h, ew, offs, icnt, selfn, nullptr, N);
  k_mgemm<128,4,2,false><<<CDIV(N,64), 256, 0, stream>>>(B0h, WT3, b3, nullptr, N, batch, gsum);
  // head
  k_gates<<<dim3(16, NG), 256, 0, stream>>>(gsum, cnt_g, wf, bf, wb, bb, gates);
  k_lstmfc<<<dim3(4, NG), 256, 0, stream>>>(gates, fw, fb, logits);
  k_smax<<<NG, 256, 0, stream>>>(logits, (float*)d_out);
}